// Round 1
// baseline (8320.086 us; speedup 1.0000x reference)
//
#include <hip/hip_runtime.h>
#include <hip/hip_bf16.h>

// Problem constants
#define NN 25000
#define EE 400000
#define S0 64
#define V0 32
#define MS 96
#define MV 96
#define OS 128
#define OV 32

// scales
#define SC_UP_S 0.125f                  // 1/sqrt(64)
#define SC_UP_V 0.17677669529663689f    // 1/sqrt(32)
#define Y1C 0.48860251190291992f
#define SC_MLP1 0.35355339059327373f    // 1/sqrt(8)
#define SC_MLP2 0.125f
#define SC3 0.0013020833333333333f      // (1/8)*(1/96)
#define INV_SQRT3 0.57735026918962584f
#define SC_DOWN 0.025515518153991442f   // 0.25 * 1/sqrt(96)  (includes 1/sqrt(16) agg scale)
#define SC_SKIP_S 0.125f
#define SC_SKIP_V 0.17677669529663689f

__device__ __forceinline__ float silu(float x) {
  return __fdividef(x, 1.f + __expf(-x));
}

// ws layout (floats)
#define WS_W1T 0
#define WS_W2T 512
#define WS_W3T 4608
#define WS_SUP 16896
#define WS_VUP (16896 + NN * S0)
#define WS_AGG (16896 + NN * S0 + NN * 96)
#define AGG_FLOATS (NN * 384)

__global__ __launch_bounds__(256) void transpose_weights(
    const float* __restrict__ W1, const float* __restrict__ W2,
    const float* __restrict__ W3, float* __restrict__ ws) {
  int t = blockIdx.x * 256 + threadIdx.x;
  int stride = gridDim.x * 256;
  // W1T[j*8+k] = W1[k*64+j]  (64x8)
  for (int i = t; i < 512; i += stride) {
    int j = i >> 3, k = i & 7;
    ws[WS_W1T + i] = W1[k * 64 + j];
  }
  // W2T[j*64+k] = W2[k*64+j] (64x64)
  for (int i = t; i < 4096; i += stride) {
    int j = i >> 6, k = i & 63;
    ws[WS_W2T + i] = W2[k * 64 + j];
  }
  // W3T[c*64+k] = W3[k*192+c] (192x64)
  for (int i = t; i < 12288; i += stride) {
    int c = i >> 6, k = i & 63;
    ws[WS_W3T + i] = W3[k * 192 + c];
  }
}

// one block per node: compute s_up (64) and v_up (32x3, layout [c*3+i])
__global__ __launch_bounds__(256) void up_kernel(
    const float* __restrict__ nf, const float* __restrict__ Wus,
    const float* __restrict__ Wuv, float* __restrict__ s_up,
    float* __restrict__ v_up) {
  int n = blockIdx.x;
  int t = threadIdx.x;
  __shared__ float sv[160];
  if (t < 160) sv[t] = nf[n * 160 + t];
  __syncthreads();
  if (t < 64) {
    float a = 0.f;
#pragma unroll
    for (int k = 0; k < 64; k++) a += sv[k] * Wus[k * 64 + t];
    s_up[n * 64 + t] = a * SC_UP_S;
  } else if (t < 160) {
    int j = t - 64;
    int c = j / 3, i = j - 3 * c;
    float a = 0.f;
#pragma unroll
    for (int k = 0; k < 32; k++) a += sv[64 + k * 3 + i] * Wuv[k * 32 + c];
    v_up[n * 96 + j] = a * SC_UP_V;
  }
}

// thread per edge
__global__ __launch_bounds__(256) void edge_kernel(
    const float* __restrict__ s_up, const float* __restrict__ v_up,
    const float* __restrict__ rbf, const float* __restrict__ vectors,
    const int* __restrict__ senders, const int* __restrict__ receivers,
    const float* __restrict__ W1T, const float* __restrict__ W2T,
    const float* __restrict__ W3T, float* __restrict__ agg) {
  int e = blockIdx.x * 256 + threadIdx.x;
  if (e >= EE) return;
  int snd = senders[e];
  int rcv = receivers[e];
  float vx = vectors[e * 3 + 0], vy = vectors[e * 3 + 1], vz = vectors[e * 3 + 2];
  float nrm = sqrtf(vx * vx + vy * vy + vz * vz) + 1e-12f;
  float ys = Y1C / nrm;
  float y0 = vx * ys, y1 = vy * ys, y2 = vz * ys;

  float4 ra = *(const float4*)(rbf + (size_t)e * 8);
  float4 rb = *(const float4*)(rbf + (size_t)e * 8 + 4);
  float r[8] = {ra.x, ra.y, ra.z, ra.w, rb.x, rb.y, rb.z, rb.w};

  float h1[64];
#pragma unroll
  for (int j = 0; j < 64; j++) {
    float4 w0 = *(const float4*)(W1T + j * 8);
    float4 w1 = *(const float4*)(W1T + j * 8 + 4);
    float a = r[0] * w0.x + r[1] * w0.y + r[2] * w0.z + r[3] * w0.w +
              r[4] * w1.x + r[5] * w1.y + r[6] * w1.z + r[7] * w1.w;
    a *= SC_MLP1;
    h1[j] = silu(a);
  }
  float h2[64];
#pragma unroll
  for (int j = 0; j < 64; j++) {
    float a = 0.f;
#pragma unroll
    for (int k = 0; k < 64; k += 4) {
      float4 w = *(const float4*)(W2T + j * 64 + k);
      a += h1[k] * w.x + h1[k + 1] * w.y + h1[k + 2] * w.z + h1[k + 3] * w.w;
    }
    a *= SC_MLP2;
    h2[j] = silu(a);
  }

  const float* se = s_up + (size_t)snd * 64;
  const float* ve = v_up + (size_t)snd * 96;
  float* aggR = agg + (size_t)rcv * 384;

  // Part 1: scalar-message channels 0..63 (s_e * mix) and tp_v channels 32..95
#pragma unroll 1
  for (int c0 = 0; c0 < 64; c0 += 4) {
    float4 se4 = *(const float4*)(se + c0);
    const float* w3s = W3T + c0 * 64;          // mix cols c0..c0+3
    const float* w3v = W3T + (128 + c0) * 64;  // mixv cols 32+c0.. (= mix col 128+c0)
    float as0 = 0, as1 = 0, as2 = 0, as3 = 0;
    float av0 = 0, av1 = 0, av2 = 0, av3 = 0;
#pragma unroll
    for (int k = 0; k < 64; k += 4) {
      float h0 = h2[k], ha = h2[k + 1], hb = h2[k + 2], hc = h2[k + 3];
      float4 a0 = *(const float4*)(w3s + k);
      float4 a1 = *(const float4*)(w3s + 64 + k);
      float4 a2 = *(const float4*)(w3s + 128 + k);
      float4 a3 = *(const float4*)(w3s + 192 + k);
      as0 += h0 * a0.x + ha * a0.y + hb * a0.z + hc * a0.w;
      as1 += h0 * a1.x + ha * a1.y + hb * a1.z + hc * a1.w;
      as2 += h0 * a2.x + ha * a2.y + hb * a2.z + hc * a2.w;
      as3 += h0 * a3.x + ha * a3.y + hb * a3.z + hc * a3.w;
      float4 b0 = *(const float4*)(w3v + k);
      float4 b1 = *(const float4*)(w3v + 64 + k);
      float4 b2 = *(const float4*)(w3v + 128 + k);
      float4 b3 = *(const float4*)(w3v + 192 + k);
      av0 += h0 * b0.x + ha * b0.y + hb * b0.z + hc * b0.w;
      av1 += h0 * b1.x + ha * b1.y + hb * b1.z + hc * b1.w;
      av2 += h0 * b2.x + ha * b2.y + hb * b2.z + hc * b2.w;
      av3 += h0 * b3.x + ha * b3.y + hb * b3.z + hc * b3.w;
    }
    float as[4] = {as0, as1, as2, as3};
    float av[4] = {av0, av1, av2, av3};
    float sev[4] = {se4.x, se4.y, se4.z, se4.w};
#pragma unroll
    for (int j = 0; j < 4; j++) {
      unsafeAtomicAdd(aggR + c0 + j, sev[j] * as[j] * SC3);
      float mv = sev[j] * av[j] * SC3;
      int base = 96 + (32 + c0 + j) * 3;
      unsafeAtomicAdd(aggR + base + 0, mv * y0);
      unsafeAtomicAdd(aggR + base + 1, mv * y1);
      unsafeAtomicAdd(aggR + base + 2, mv * y2);
    }
  }

  // Part 2: tp_s channels 64..95 and v_e vector channels 0..31
#pragma unroll 1
  for (int c0 = 0; c0 < 32; c0 += 4) {
    float4 va = *(const float4*)(ve + c0 * 3);
    float4 vb = *(const float4*)(ve + c0 * 3 + 4);
    float4 vc = *(const float4*)(ve + c0 * 3 + 8);
    float vex[4] = {va.x, va.w, vb.z, vc.y};
    float vey[4] = {va.y, vb.x, vb.w, vc.z};
    float vez[4] = {va.z, vb.y, vc.x, vc.w};
    const float* w3s = W3T + (64 + c0) * 64;  // mix cols 64+c0
    const float* w3v = W3T + (96 + c0) * 64;  // mixv cols c0 (= mix col 96+c0)
    float as0 = 0, as1 = 0, as2 = 0, as3 = 0;
    float av0 = 0, av1 = 0, av2 = 0, av3 = 0;
#pragma unroll
    for (int k = 0; k < 64; k += 4) {
      float h0 = h2[k], ha = h2[k + 1], hb = h2[k + 2], hc = h2[k + 3];
      float4 a0 = *(const float4*)(w3s + k);
      float4 a1 = *(const float4*)(w3s + 64 + k);
      float4 a2 = *(const float4*)(w3s + 128 + k);
      float4 a3 = *(const float4*)(w3s + 192 + k);
      as0 += h0 * a0.x + ha * a0.y + hb * a0.z + hc * a0.w;
      as1 += h0 * a1.x + ha * a1.y + hb * a1.z + hc * a1.w;
      as2 += h0 * a2.x + ha * a2.y + hb * a2.z + hc * a2.w;
      as3 += h0 * a3.x + ha * a3.y + hb * a3.z + hc * a3.w;
      float4 b0 = *(const float4*)(w3v + k);
      float4 b1 = *(const float4*)(w3v + 64 + k);
      float4 b2 = *(const float4*)(w3v + 128 + k);
      float4 b3 = *(const float4*)(w3v + 192 + k);
      av0 += h0 * b0.x + ha * b0.y + hb * b0.z + hc * b0.w;
      av1 += h0 * b1.x + ha * b1.y + hb * b1.z + hc * b1.w;
      av2 += h0 * b2.x + ha * b2.y + hb * b2.z + hc * b2.w;
      av3 += h0 * b3.x + ha * b3.y + hb * b3.z + hc * b3.w;
    }
    float as[4] = {as0, as1, as2, as3};
    float av[4] = {av0, av1, av2, av3};
#pragma unroll
    for (int j = 0; j < 4; j++) {
      float tps = (vex[j] * y0 + vey[j] * y1 + vez[j] * y2) * INV_SQRT3;
      unsafeAtomicAdd(aggR + 64 + c0 + j, tps * as[j] * SC3);
      float mv = av[j] * SC3;
      int base = 96 + (c0 + j) * 3;
      unsafeAtomicAdd(aggR + base + 0, vex[j] * mv);
      unsafeAtomicAdd(aggR + base + 1, vey[j] * mv);
      unsafeAtomicAdd(aggR + base + 2, vez[j] * mv);
    }
  }
}

// one block per node: down-proj + skip + gating -> output (192 floats/node)
__global__ __launch_bounds__(256) void out_kernel(
    const float* __restrict__ nf, const int* __restrict__ species,
    const float* __restrict__ agg, const float* __restrict__ Wds,
    const float* __restrict__ Wdv, const float* __restrict__ Wss,
    const float* __restrict__ Wsv, float* __restrict__ out) {
  int n = blockIdx.x;
  int t = threadIdx.x;
  __shared__ float sAgg[384];
  __shared__ float sNF[160];
  __shared__ float sF[224];  // f_s[128], f_v[96]
  if (t < 160) sNF[t] = nf[n * 160 + t];
  sAgg[t] = agg[(size_t)n * 384 + t];
  if (t < 128) sAgg[256 + t] = agg[(size_t)n * 384 + 256 + t];
  __syncthreads();
  int spec = species[n];
  if (t < 128) {
    float a = 0.f;
#pragma unroll
    for (int k = 0; k < 96; k++) a += sAgg[k] * Wds[k * 128 + t];
    a *= SC_DOWN;
    const float* wsk = Wss + spec * 64 * 128;
    float b = 0.f;
#pragma unroll
    for (int k = 0; k < 64; k++) b += sNF[k] * wsk[k * 128 + t];
    sF[t] = a + b * SC_SKIP_S;
  } else if (t < 224) {
    int j = t - 128;
    int c = j / 3, i = j - 3 * c;
    float a = 0.f;
#pragma unroll
    for (int k = 0; k < 96; k++) a += sAgg[96 + k * 3 + i] * Wdv[k * 32 + c];
    a *= SC_DOWN;
    const float* wsk = Wsv + spec * 32 * 32;
    float b = 0.f;
#pragma unroll
    for (int k = 0; k < 32; k++) b += sNF[64 + k * 3 + i] * wsk[k * 32 + c];
    sF[128 + j] = a + b * SC_SKIP_V;
  }
  __syncthreads();
  if (t < 96) {
    out[(size_t)n * 192 + t] = silu(sF[t]);
  } else if (t < 192) {
    int j = t - 96;
    int c = j / 3;
    float g = silu(sF[96 + c]);
    out[(size_t)n * 192 + t] = sF[128 + j] * g;
  }
}

extern "C" void kernel_launch(void* const* d_in, const int* in_sizes, int n_in,
                              void* d_out, int out_size, void* d_ws, size_t ws_size,
                              hipStream_t stream) {
  const float* nf = (const float*)d_in[0];
  const float* vectors = (const float*)d_in[1];
  const float* rbf = (const float*)d_in[2];
  const int* species = (const int*)d_in[3];
  const int* senders = (const int*)d_in[4];
  const int* receivers = (const int*)d_in[5];
  const float* Wus = (const float*)d_in[6];
  const float* Wuv = (const float*)d_in[7];
  const float* W1 = (const float*)d_in[8];
  const float* W2 = (const float*)d_in[9];
  const float* W3 = (const float*)d_in[10];
  const float* Wds = (const float*)d_in[11];
  const float* Wdv = (const float*)d_in[12];
  const float* Wss = (const float*)d_in[13];
  const float* Wsv = (const float*)d_in[14];

  float* ws = (float*)d_ws;
  float* W1T = ws + WS_W1T;
  float* W2T = ws + WS_W2T;
  float* W3T = ws + WS_W3T;
  float* s_up = ws + WS_SUP;
  float* v_up = ws + WS_VUP;
  float* agg = ws + WS_AGG;
  float* out = (float*)d_out;

  // zero aggregation buffer (must be fresh every call)
  hipMemsetAsync(agg, 0, (size_t)AGG_FLOATS * sizeof(float), stream);
  transpose_weights<<<16, 256, 0, stream>>>(W1, W2, W3, ws);
  up_kernel<<<NN, 256, 0, stream>>>(nf, Wus, Wuv, s_up, v_up);
  edge_kernel<<<(EE + 255) / 256, 256, 0, stream>>>(
      s_up, v_up, rbf, vectors, senders, receivers, W1T, W2T, W3T, agg);
  out_kernel<<<NN, 256, 0, stream>>>(nf, species, agg, Wds, Wdv, Wss, Wsv, out);
}

// Round 2
// 1799.309 us; speedup vs baseline: 4.6240x; 4.6240x over previous
//
#include <hip/hip_runtime.h>
#include <hip/hip_bf16.h>
#include <hip/hip_fp16.h>

// Problem constants
#define NN 25000
#define EE 400000

// scales
#define SC_UP_S 0.125f                  // 1/sqrt(64)
#define SC_UP_V 0.17677669529663689f    // 1/sqrt(32)
#define Y1C 0.48860251190291992f
#define SC_MLP1 0.35355339059327373f    // 1/sqrt(8)
#define SC_MLP2 0.125f
#define SC3 0.0013020833333333333f      // (1/8)*(1/96)
#define INV_SQRT3 0.57735026918962584f
#define SC_DOWN 0.025515518153991442f   // (1/4) * (1/sqrt(96))
#define SC_SKIP_S 0.125f
#define SC_SKIP_V 0.17677669529663689f

__device__ __forceinline__ float silu(float x) {
  return __fdividef(x, 1.f + __expf(-x));
}

// ------------------- workspace layout (4-byte word offsets) -------------------
#define W_W1T 0
#define W_W2T 512
#define W_W3T 4608
#define W_SUP 16896
#define W_VUP (W_SUP + NN * 64)          // 1616896
#define W_Y   (W_VUP + NN * 96)          // 4016896  (float4 per edge)
#define W_MIX (W_Y + EE * 4)             // 5616896  (EE*192 halves = EE*96 words)
#define W_DEG (W_MIX + EE * 96)          // 44016896
#define W_PRE (W_DEG + NN + 8)
#define W_CUR (W_PRE + NN + 8)
#define W_SRT (W_CUR + NN + 8)           // int2 per edge (even word offset)
#define W_END (W_SRT + EE * 2)           // ~44.9M words ~ 179.6 MB
// fallback aliases agg at W_Y
#define W_AGG_FB W_Y
#define W_END_FB (W_AGG_FB + NN * 384)   // ~54.5 MB

// ------------------- weight transpose + scale folding -------------------
__global__ __launch_bounds__(256) void transpose_weights(
    const float* __restrict__ W1, const float* __restrict__ W2,
    const float* __restrict__ W3, float* __restrict__ ws) {
  int t = blockIdx.x * 256 + threadIdx.x;
  int stride = gridDim.x * 256;
  for (int i = t; i < 512; i += stride) {      // W1T[j*8+k] = W1[k*64+j] * sc
    int j = i >> 3, k = i & 7;
    ws[W_W1T + i] = W1[k * 64 + j] * SC_MLP1;
  }
  for (int i = t; i < 4096; i += stride) {     // W2T[j*64+k]
    int j = i >> 6, k = i & 63;
    ws[W_W2T + i] = W2[k * 64 + j] * SC_MLP2;
  }
  for (int i = t; i < 12288; i += stride) {    // W3T[c*64+k]
    int c = i >> 6, k = i & 63;
    ws[W_W3T + i] = W3[k * 192 + c] * SC3;
  }
}

// ------------------- per-node up-projection -------------------
__global__ __launch_bounds__(256) void up_kernel(
    const float* __restrict__ nf, const float* __restrict__ Wus,
    const float* __restrict__ Wuv, float* __restrict__ s_up,
    float* __restrict__ v_up) {
  int n = blockIdx.x;
  int t = threadIdx.x;
  __shared__ float sv[160];
  if (t < 160) sv[t] = nf[n * 160 + t];
  __syncthreads();
  if (t < 64) {
    float a = 0.f;
#pragma unroll
    for (int k = 0; k < 64; k++) a += sv[k] * Wus[k * 64 + t];
    s_up[n * 64 + t] = a * SC_UP_S;
  } else if (t < 160) {
    int j = t - 64;
    int c = j / 3, i = j - 3 * c;
    float a = 0.f;
#pragma unroll
    for (int k = 0; k < 32; k++) a += sv[64 + k * 3 + i] * Wuv[k * 32 + c];
    v_up[n * 96 + j] = a * SC_UP_V;
  }
}

// ------------------- counting sort by receiver -------------------
__global__ __launch_bounds__(256) void count_deg(
    const int* __restrict__ receivers, int* __restrict__ deg) {
  int e = blockIdx.x * 256 + threadIdx.x;
  if (e < EE) atomicAdd(&deg[receivers[e]], 1);
}

__global__ __launch_bounds__(1024) void scan_kernel(
    const int* __restrict__ deg, int* __restrict__ prefix) {
  __shared__ int waveSums[16];
  __shared__ int sCarry;
  int t = threadIdx.x;
  int lane = t & 63, wv = t >> 6;
  if (t == 0) sCarry = 0;
  __syncthreads();
  for (int base = 0; base < NN; base += 1024) {
    int i = base + t;
    int x = (i < NN) ? deg[i] : 0;
    int v = x;
#pragma unroll
    for (int d = 1; d < 64; d <<= 1) {
      int u = __shfl_up(v, d, 64);
      if (lane >= d) v += u;
    }
    if (lane == 63) waveSums[wv] = v;
    __syncthreads();
    if (wv == 0 && lane < 16) {
      int s = waveSums[lane];
#pragma unroll
      for (int d = 1; d < 16; d <<= 1) {
        int u = __shfl_up(s, d, 64);
        if (lane >= d) s += u;
      }
      waveSums[lane] = s;  // inclusive
    }
    __syncthreads();
    int waveOff = (wv == 0) ? 0 : waveSums[wv - 1];
    int incl = v + waveOff + sCarry;
    if (i < NN) prefix[i] = incl - x;  // exclusive
    __syncthreads();
    if (t == 1023) sCarry = incl;
    __syncthreads();
  }
  if (t == 0) prefix[NN] = sCarry;  // == EE
}

__global__ __launch_bounds__(256) void copy_cursor(
    const int* __restrict__ prefix, int* __restrict__ cursor) {
  int i = blockIdx.x * 256 + threadIdx.x;
  if (i < NN) cursor[i] = prefix[i];
}

__global__ __launch_bounds__(256) void scatter_kernel(
    const int* __restrict__ senders, const int* __restrict__ receivers,
    int* __restrict__ cursor, int2* __restrict__ sorted) {
  int e = blockIdx.x * 256 + threadIdx.x;
  if (e < EE) {
    int r = receivers[e];
    int pos = atomicAdd(&cursor[r], 1);
    sorted[pos] = make_int2(e, senders[e]);
  }
}

// ------------------- per-edge MLP -> mix (fp16) + y -------------------
__global__ __launch_bounds__(256) void edge_mlp_kernel(
    const float* __restrict__ rbf, const float* __restrict__ vectors,
    const float* __restrict__ W1T, const float* __restrict__ W2T,
    const float* __restrict__ W3T, __half* __restrict__ mixH,
    float4* __restrict__ ybuf) {
  int e = blockIdx.x * 256 + threadIdx.x;
  if (e >= EE) return;
  float vx = vectors[e * 3 + 0], vy = vectors[e * 3 + 1], vz = vectors[e * 3 + 2];
  float nrm = sqrtf(vx * vx + vy * vy + vz * vz) + 1e-12f;
  float ys = Y1C / nrm;
  ybuf[e] = make_float4(vx * ys, vy * ys, vz * ys, 0.f);

  float4 ra = *(const float4*)(rbf + (size_t)e * 8);
  float4 rb = *(const float4*)(rbf + (size_t)e * 8 + 4);
  float r[8] = {ra.x, ra.y, ra.z, ra.w, rb.x, rb.y, rb.z, rb.w};

  float h1[64];
#pragma unroll
  for (int j = 0; j < 64; j++) {
    float4 w0 = *(const float4*)(W1T + j * 8);
    float4 w1 = *(const float4*)(W1T + j * 8 + 4);
    float a = r[0] * w0.x + r[1] * w0.y + r[2] * w0.z + r[3] * w0.w +
              r[4] * w1.x + r[5] * w1.y + r[6] * w1.z + r[7] * w1.w;
    h1[j] = silu(a);
  }
  float h2[64];
#pragma unroll
  for (int j = 0; j < 64; j++) {
    float a = 0.f;
#pragma unroll
    for (int k = 0; k < 64; k += 4) {
      float4 w = *(const float4*)(W2T + j * 64 + k);
      a += h1[k] * w.x + h1[k + 1] * w.y + h1[k + 2] * w.z + h1[k + 3] * w.w;
    }
    h2[j] = silu(a);
  }

  __half* mout = mixH + (size_t)e * 192;
#pragma unroll 1
  for (int c0 = 0; c0 < 192; c0 += 8) {
    float acc[8] = {0, 0, 0, 0, 0, 0, 0, 0};
    const float* w = W3T + c0 * 64;
#pragma unroll
    for (int k = 0; k < 64; k += 4) {
      float h0 = h2[k], ha = h2[k + 1], hb = h2[k + 2], hc = h2[k + 3];
#pragma unroll
      for (int j = 0; j < 8; j++) {
        float4 wv = *(const float4*)(w + j * 64 + k);
        acc[j] += h0 * wv.x + ha * wv.y + hb * wv.z + hc * wv.w;
      }
    }
    uint4 pk;
    pk.x = ((unsigned)__half_as_ushort(__float2half_rn(acc[1])) << 16) |
           (unsigned)__half_as_ushort(__float2half_rn(acc[0]));
    pk.y = ((unsigned)__half_as_ushort(__float2half_rn(acc[3])) << 16) |
           (unsigned)__half_as_ushort(__float2half_rn(acc[2]));
    pk.z = ((unsigned)__half_as_ushort(__float2half_rn(acc[5])) << 16) |
           (unsigned)__half_as_ushort(__float2half_rn(acc[4]));
    pk.w = ((unsigned)__half_as_ushort(__float2half_rn(acc[7])) << 16) |
           (unsigned)__half_as_ushort(__float2half_rn(acc[6]));
    *(uint4*)(mout + c0) = pk;
  }
}

// ------------------- fused gather + down-proj + skip + gate -------------------
__global__ __launch_bounds__(384) void gather_out_kernel(
    const float* __restrict__ nf, const int* __restrict__ species,
    const int2* __restrict__ sorted, const int* __restrict__ prefix,
    const float* __restrict__ s_up, const float* __restrict__ v_up,
    const __half* __restrict__ mixH, const float4* __restrict__ ybuf,
    const float* __restrict__ Wds, const float* __restrict__ Wdv,
    const float* __restrict__ Wss, const float* __restrict__ Wsv,
    float* __restrict__ out) {
  int n = blockIdx.x;
  int t = threadIdx.x;
  __shared__ float sSE[64];
  __shared__ float sVE[96];
  __shared__ float sMIX[192];
  __shared__ float sY[4];
  __shared__ float sAgg[384];
  __shared__ float sNF[160];
  __shared__ float sF[224];

  if (t < 160) sNF[t] = nf[n * 160 + t];

  int beg = prefix[n], end = prefix[n + 1];
  // channel mapping for t >= 96
  int j = t - 96;
  int c = j / 3, ii = j - 3 * c;

  float acc = 0.f;
  for (int it = beg; it < end; ++it) {
    int2 es = sorted[it];
    int e = es.x, snd = es.y;
    __syncthreads();
    if (t < 64) sSE[t] = s_up[(size_t)snd * 64 + t];
    else if (t < 160) sVE[t - 64] = v_up[(size_t)snd * 96 + (t - 64)];
    else if (t < 352) sMIX[t - 160] = __half2float(mixH[(size_t)e * 192 + (t - 160)]);
    else if (t == 352) {
      float4 y = ybuf[e];
      sY[0] = y.x; sY[1] = y.y; sY[2] = y.z;
    }
    __syncthreads();
    if (t < 64) {
      acc += sSE[t] * sMIX[t];
    } else if (t < 96) {
      int cc = t - 64;
      float d = sVE[cc * 3 + 0] * sY[0] + sVE[cc * 3 + 1] * sY[1] +
                sVE[cc * 3 + 2] * sY[2];
      acc += d * INV_SQRT3 * sMIX[t];
    } else {
      float base = (c < 32) ? sVE[c * 3 + ii] : sSE[c - 32] * sY[ii];
      acc += base * sMIX[96 + c];
    }
  }
  __syncthreads();
  sAgg[t] = acc;
  __syncthreads();

  int spec = species[n];
  if (t < 128) {
    float a = 0.f;
#pragma unroll
    for (int k = 0; k < 96; k++) a += sAgg[k] * Wds[k * 128 + t];
    a *= SC_DOWN;
    const float* wsk = Wss + spec * 64 * 128;
    float b = 0.f;
#pragma unroll
    for (int k = 0; k < 64; k++) b += sNF[k] * wsk[k * 128 + t];
    sF[t] = a + b * SC_SKIP_S;
  } else if (t < 224) {
    int jj = t - 128;
    int cc = jj / 3, i2 = jj - 3 * cc;
    float a = 0.f;
#pragma unroll
    for (int k = 0; k < 96; k++) a += sAgg[96 + k * 3 + i2] * Wdv[k * 32 + cc];
    a *= SC_DOWN;
    const float* wsk = Wsv + spec * 32 * 32;
    float b = 0.f;
#pragma unroll
    for (int k = 0; k < 32; k++) b += sNF[64 + k * 3 + i2] * wsk[k * 32 + cc];
    sF[128 + jj] = a + b * SC_SKIP_V;
  }
  __syncthreads();
  if (t < 96) {
    out[(size_t)n * 192 + t] = silu(sF[t]);
  } else if (t < 192) {
    int jj = t - 96;
    int cc = jj / 3;
    float g = silu(sF[96 + cc]);
    out[(size_t)n * 192 + t] = sF[128 + jj] * g;
  }
}

// ------------------- fallback: round-1 atomic edge kernel -------------------
__global__ __launch_bounds__(256) void edge_kernel_atomic(
    const float* __restrict__ s_up, const float* __restrict__ v_up,
    const float* __restrict__ rbf, const float* __restrict__ vectors,
    const int* __restrict__ senders, const int* __restrict__ receivers,
    const float* __restrict__ W1T, const float* __restrict__ W2T,
    const float* __restrict__ W3T, float* __restrict__ agg) {
  int e = blockIdx.x * 256 + threadIdx.x;
  if (e >= EE) return;
  int snd = senders[e];
  int rcv = receivers[e];
  float vx = vectors[e * 3 + 0], vy = vectors[e * 3 + 1], vz = vectors[e * 3 + 2];
  float nrm = sqrtf(vx * vx + vy * vy + vz * vz) + 1e-12f;
  float ys = Y1C / nrm;
  float y0 = vx * ys, y1 = vy * ys, y2 = vz * ys;

  float4 ra = *(const float4*)(rbf + (size_t)e * 8);
  float4 rb = *(const float4*)(rbf + (size_t)e * 8 + 4);
  float r[8] = {ra.x, ra.y, ra.z, ra.w, rb.x, rb.y, rb.z, rb.w};

  float h1[64];
#pragma unroll
  for (int j = 0; j < 64; j++) {
    float4 w0 = *(const float4*)(W1T + j * 8);
    float4 w1 = *(const float4*)(W1T + j * 8 + 4);
    float a = r[0] * w0.x + r[1] * w0.y + r[2] * w0.z + r[3] * w0.w +
              r[4] * w1.x + r[5] * w1.y + r[6] * w1.z + r[7] * w1.w;
    h1[j] = silu(a);
  }
  float h2[64];
#pragma unroll
  for (int j = 0; j < 64; j++) {
    float a = 0.f;
#pragma unroll
    for (int k = 0; k < 64; k += 4) {
      float4 w = *(const float4*)(W2T + j * 64 + k);
      a += h1[k] * w.x + h1[k + 1] * w.y + h1[k + 2] * w.z + h1[k + 3] * w.w;
    }
    h2[j] = silu(a);
  }

  const float* se = s_up + (size_t)snd * 64;
  const float* ve = v_up + (size_t)snd * 96;
  float* aggR = agg + (size_t)rcv * 384;

#pragma unroll 1
  for (int c0 = 0; c0 < 64; c0 += 4) {
    float4 se4 = *(const float4*)(se + c0);
    const float* w3s = W3T + c0 * 64;
    const float* w3v = W3T + (128 + c0) * 64;
    float as0 = 0, as1 = 0, as2 = 0, as3 = 0;
    float av0 = 0, av1 = 0, av2 = 0, av3 = 0;
#pragma unroll
    for (int k = 0; k < 64; k += 4) {
      float h0 = h2[k], ha = h2[k + 1], hb = h2[k + 2], hc = h2[k + 3];
      float4 a0 = *(const float4*)(w3s + k);
      float4 a1 = *(const float4*)(w3s + 64 + k);
      float4 a2 = *(const float4*)(w3s + 128 + k);
      float4 a3 = *(const float4*)(w3s + 192 + k);
      as0 += h0 * a0.x + ha * a0.y + hb * a0.z + hc * a0.w;
      as1 += h0 * a1.x + ha * a1.y + hb * a1.z + hc * a1.w;
      as2 += h0 * a2.x + ha * a2.y + hb * a2.z + hc * a2.w;
      as3 += h0 * a3.x + ha * a3.y + hb * a3.z + hc * a3.w;
      float4 b0 = *(const float4*)(w3v + k);
      float4 b1 = *(const float4*)(w3v + 64 + k);
      float4 b2 = *(const float4*)(w3v + 128 + k);
      float4 b3 = *(const float4*)(w3v + 192 + k);
      av0 += h0 * b0.x + ha * b0.y + hb * b0.z + hc * b0.w;
      av1 += h0 * b1.x + ha * b1.y + hb * b1.z + hc * b1.w;
      av2 += h0 * b2.x + ha * b2.y + hb * b2.z + hc * b2.w;
      av3 += h0 * b3.x + ha * b3.y + hb * b3.z + hc * b3.w;
    }
    float as[4] = {as0, as1, as2, as3};
    float av[4] = {av0, av1, av2, av3};
    float sev[4] = {se4.x, se4.y, se4.z, se4.w};
#pragma unroll
    for (int j = 0; j < 4; j++) {
      unsafeAtomicAdd(aggR + c0 + j, sev[j] * as[j]);
      float mv = sev[j] * av[j];
      int base = 96 + (32 + c0 + j) * 3;
      unsafeAtomicAdd(aggR + base + 0, mv * y0);
      unsafeAtomicAdd(aggR + base + 1, mv * y1);
      unsafeAtomicAdd(aggR + base + 2, mv * y2);
    }
  }

#pragma unroll 1
  for (int c0 = 0; c0 < 32; c0 += 4) {
    float4 va = *(const float4*)(ve + c0 * 3);
    float4 vb = *(const float4*)(ve + c0 * 3 + 4);
    float4 vc = *(const float4*)(ve + c0 * 3 + 8);
    float vex[4] = {va.x, va.w, vb.z, vc.y};
    float vey[4] = {va.y, vb.x, vb.w, vc.z};
    float vez[4] = {va.z, vb.y, vc.x, vc.w};
    const float* w3s = W3T + (64 + c0) * 64;
    const float* w3v = W3T + (96 + c0) * 64;
    float as0 = 0, as1 = 0, as2 = 0, as3 = 0;
    float av0 = 0, av1 = 0, av2 = 0, av3 = 0;
#pragma unroll
    for (int k = 0; k < 64; k += 4) {
      float h0 = h2[k], ha = h2[k + 1], hb = h2[k + 2], hc = h2[k + 3];
      float4 a0 = *(const float4*)(w3s + k);
      float4 a1 = *(const float4*)(w3s + 64 + k);
      float4 a2 = *(const float4*)(w3s + 128 + k);
      float4 a3 = *(const float4*)(w3s + 192 + k);
      as0 += h0 * a0.x + ha * a0.y + hb * a0.z + hc * a0.w;
      as1 += h0 * a1.x + ha * a1.y + hb * a1.z + hc * a1.w;
      as2 += h0 * a2.x + ha * a2.y + hb * a2.z + hc * a2.w;
      as3 += h0 * a3.x + ha * a3.y + hb * a3.z + hc * a3.w;
      float4 b0 = *(const float4*)(w3v + k);
      float4 b1 = *(const float4*)(w3v + 64 + k);
      float4 b2 = *(const float4*)(w3v + 128 + k);
      float4 b3 = *(const float4*)(w3v + 192 + k);
      av0 += h0 * b0.x + ha * b0.y + hb * b0.z + hc * b0.w;
      av1 += h0 * b1.x + ha * b1.y + hb * b1.z + hc * b1.w;
      av2 += h0 * b2.x + ha * b2.y + hb * b2.z + hc * b2.w;
      av3 += h0 * b3.x + ha * b3.y + hb * b3.z + hc * b3.w;
    }
    float as[4] = {as0, as1, as2, as3};
    float av[4] = {av0, av1, av2, av3};
#pragma unroll
    for (int j = 0; j < 4; j++) {
      float tps = (vex[j] * y0 + vey[j] * y1 + vez[j] * y2) * INV_SQRT3;
      unsafeAtomicAdd(aggR + 64 + c0 + j, tps * as[j]);
      float mv = av[j];
      int base = 96 + (c0 + j) * 3;
      unsafeAtomicAdd(aggR + base + 0, vex[j] * mv);
      unsafeAtomicAdd(aggR + base + 1, vey[j] * mv);
      unsafeAtomicAdd(aggR + base + 2, vez[j] * mv);
    }
  }
}

__global__ __launch_bounds__(256) void out_kernel_fb(
    const float* __restrict__ nf, const int* __restrict__ species,
    const float* __restrict__ agg, const float* __restrict__ Wds,
    const float* __restrict__ Wdv, const float* __restrict__ Wss,
    const float* __restrict__ Wsv, float* __restrict__ out) {
  int n = blockIdx.x;
  int t = threadIdx.x;
  __shared__ float sAgg[384];
  __shared__ float sNF[160];
  __shared__ float sF[224];
  if (t < 160) sNF[t] = nf[n * 160 + t];
  sAgg[t] = agg[(size_t)n * 384 + t];
  if (t < 128) sAgg[256 + t] = agg[(size_t)n * 384 + 256 + t];
  __syncthreads();
  int spec = species[n];
  if (t < 128) {
    float a = 0.f;
#pragma unroll
    for (int k = 0; k < 96; k++) a += sAgg[k] * Wds[k * 128 + t];
    a *= SC_DOWN;
    const float* wsk = Wss + spec * 64 * 128;
    float b = 0.f;
#pragma unroll
    for (int k = 0; k < 64; k++) b += sNF[k] * wsk[k * 128 + t];
    sF[t] = a + b * SC_SKIP_S;
  } else if (t < 224) {
    int j = t - 128;
    int c = j / 3, i = j - 3 * c;
    float a = 0.f;
#pragma unroll
    for (int k = 0; k < 96; k++) a += sAgg[96 + k * 3 + i] * Wdv[k * 32 + c];
    a *= SC_DOWN;
    const float* wsk = Wsv + spec * 32 * 32;
    float b = 0.f;
#pragma unroll
    for (int k = 0; k < 32; k++) b += sNF[64 + k * 3 + i] * wsk[k * 32 + c];
    sF[128 + j] = a + b * SC_SKIP_V;
  }
  __syncthreads();
  if (t < 96) {
    out[(size_t)n * 192 + t] = silu(sF[t]);
  } else if (t < 192) {
    int j = t - 96;
    int c = j / 3;
    float g = silu(sF[96 + c]);
    out[(size_t)n * 192 + t] = sF[128 + j] * g;
  }
}

extern "C" void kernel_launch(void* const* d_in, const int* in_sizes, int n_in,
                              void* d_out, int out_size, void* d_ws, size_t ws_size,
                              hipStream_t stream) {
  const float* nf = (const float*)d_in[0];
  const float* vectors = (const float*)d_in[1];
  const float* rbf = (const float*)d_in[2];
  const int* species = (const int*)d_in[3];
  const int* senders = (const int*)d_in[4];
  const int* receivers = (const int*)d_in[5];
  const float* Wus = (const float*)d_in[6];
  const float* Wuv = (const float*)d_in[7];
  const float* W1 = (const float*)d_in[8];
  const float* W2 = (const float*)d_in[9];
  const float* W3 = (const float*)d_in[10];
  const float* Wds = (const float*)d_in[11];
  const float* Wdv = (const float*)d_in[12];
  const float* Wss = (const float*)d_in[13];
  const float* Wsv = (const float*)d_in[14];

  float* ws = (float*)d_ws;
  float* W1T = ws + W_W1T;
  float* W2T = ws + W_W2T;
  float* W3T = ws + W_W3T;
  float* s_up = ws + W_SUP;
  float* v_up = ws + W_VUP;
  float* out = (float*)d_out;

  transpose_weights<<<16, 256, 0, stream>>>(W1, W2, W3, ws);
  up_kernel<<<NN, 256, 0, stream>>>(nf, Wus, Wuv, s_up, v_up);

  if (ws_size >= (size_t)W_END * 4) {
    // ---- fast path: counting sort + gather, no fp32 atomics ----
    float4* ybuf = (float4*)(ws + W_Y);
    __half* mixH = (__half*)(ws + W_MIX);
    int* deg = (int*)(ws + W_DEG);
    int* prefix = (int*)(ws + W_PRE);
    int* cursor = (int*)(ws + W_CUR);
    int2* sorted = (int2*)(ws + W_SRT);

    hipMemsetAsync(deg, 0, (size_t)NN * sizeof(int), stream);
    count_deg<<<(EE + 255) / 256, 256, 0, stream>>>(receivers, deg);
    scan_kernel<<<1, 1024, 0, stream>>>(deg, prefix);
    copy_cursor<<<(NN + 255) / 256, 256, 0, stream>>>(prefix, cursor);
    scatter_kernel<<<(EE + 255) / 256, 256, 0, stream>>>(senders, receivers,
                                                         cursor, sorted);
    edge_mlp_kernel<<<(EE + 255) / 256, 256, 0, stream>>>(
        rbf, vectors, W1T, W2T, W3T, mixH, ybuf);
    gather_out_kernel<<<NN, 384, 0, stream>>>(
        nf, species, sorted, prefix, s_up, v_up, mixH, ybuf, Wds, Wdv, Wss,
        Wsv, out);
  } else {
    // ---- fallback: atomic scatter (round-1 structure) ----
    float* agg = ws + W_AGG_FB;
    hipMemsetAsync(agg, 0, (size_t)NN * 384 * sizeof(float), stream);
    edge_kernel_atomic<<<(EE + 255) / 256, 256, 0, stream>>>(
        s_up, v_up, rbf, vectors, senders, receivers, W1T, W2T, W3T, agg);
    out_kernel_fb<<<NN, 256, 0, stream>>>(nf, species, agg, Wds, Wdv, Wss,
                                          Wsv, out);
  }
}

// Round 3
// 976.348 us; speedup vs baseline: 8.5216x; 1.8429x over previous
//
#include <hip/hip_runtime.h>
#include <hip/hip_bf16.h>
#include <hip/hip_fp16.h>

// Problem constants
#define NN 25000
#define EE 400000

// scales
#define SC_UP_S 0.125f                  // 1/sqrt(64)
#define SC_UP_V 0.17677669529663689f    // 1/sqrt(32)
#define Y1C 0.48860251190291992f
#define SC_MLP1 0.35355339059327373f    // 1/sqrt(8)
#define SC_MLP2 0.125f
#define SC3 0.0013020833333333333f      // (1/8)*(1/96)
#define INV_SQRT3 0.57735026918962584f
#define SC_DOWN 0.025515518153991442f   // (1/4) * (1/sqrt(96))
#define SC_SKIP_S 0.125f
#define SC_SKIP_V 0.17677669529663689f

typedef __attribute__((ext_vector_type(8))) short short8;
typedef __attribute__((ext_vector_type(4))) float f32x4;

__device__ __forceinline__ float silu(float x) {
  return __fdividef(x, 1.f + __expf(-x));
}

__device__ __forceinline__ unsigned short f2bf(float f) {
  unsigned u = __float_as_uint(f);
  unsigned r = u + 0x7FFF + ((u >> 16) & 1);
  return (unsigned short)(r >> 16);
}

__device__ __forceinline__ float h2f(unsigned short s) {
  __half_raw r;
  r.x = s;
  return __half2float(__half(r));
}

// ------------------- workspace layout (4-byte word offsets) -------------------
#define W_W1T 0
#define W_W2T 512
#define W_W3T 4608
#define W_SUP 16896
#define W_VUP (W_SUP + NN * 64)
#define W_Y   (W_VUP + NN * 96)          // float4 per sorted slot
#define W_MIX (W_Y + EE * 4)             // EE*192 halves (sorted order)
#define W_DEG (W_MIX + EE * 96)
#define W_PRE (W_DEG + NN + 8)
#define W_CUR (W_PRE + NN + 8)
#define W_SRT (W_CUR + NN + 8)           // int2 per edge
#define W_END (W_SRT + EE * 2)

// ------------------- weight transpose + scale folding -------------------
__global__ __launch_bounds__(256) void transpose_weights(
    const float* __restrict__ W1, const float* __restrict__ W2,
    const float* __restrict__ W3, float* __restrict__ ws) {
  int t = blockIdx.x * 256 + threadIdx.x;
  int stride = gridDim.x * 256;
  for (int i = t; i < 512; i += stride) {      // W1T[j*8+k] = W1[k*64+j] * sc
    int j = i >> 3, k = i & 7;
    ws[W_W1T + i] = W1[k * 64 + j] * SC_MLP1;
  }
  for (int i = t; i < 4096; i += stride) {     // W2T[j*64+k]
    int j = i >> 6, k = i & 63;
    ws[W_W2T + i] = W2[k * 64 + j] * SC_MLP2;
  }
  for (int i = t; i < 12288; i += stride) {    // W3T[c*64+k]
    int c = i >> 6, k = i & 63;
    ws[W_W3T + i] = W3[k * 192 + c] * SC3;
  }
}

// ------------------- per-node up-projection -------------------
__global__ __launch_bounds__(256) void up_kernel(
    const float* __restrict__ nf, const float* __restrict__ Wus,
    const float* __restrict__ Wuv, float* __restrict__ s_up,
    float* __restrict__ v_up) {
  int n = blockIdx.x;
  int t = threadIdx.x;
  __shared__ float sv[160];
  if (t < 160) sv[t] = nf[n * 160 + t];
  __syncthreads();
  if (t < 64) {
    float a = 0.f;
#pragma unroll
    for (int k = 0; k < 64; k++) a += sv[k] * Wus[k * 64 + t];
    s_up[n * 64 + t] = a * SC_UP_S;
  } else if (t < 160) {
    int j = t - 64;
    int c = j / 3, i = j - 3 * c;
    float a = 0.f;
#pragma unroll
    for (int k = 0; k < 32; k++) a += sv[64 + k * 3 + i] * Wuv[k * 32 + c];
    v_up[n * 96 + j] = a * SC_UP_V;
  }
}

// ------------------- counting sort by receiver -------------------
__global__ __launch_bounds__(256) void count_deg(
    const int* __restrict__ receivers, int* __restrict__ deg) {
  int e = blockIdx.x * 256 + threadIdx.x;
  if (e < EE) atomicAdd(&deg[receivers[e]], 1);
}

__global__ __launch_bounds__(1024) void scan_kernel(
    const int* __restrict__ deg, int* __restrict__ prefix) {
  __shared__ int waveSums[16];
  __shared__ int sCarry;
  int t = threadIdx.x;
  int lane = t & 63, wv = t >> 6;
  if (t == 0) sCarry = 0;
  __syncthreads();
  for (int base = 0; base < NN; base += 1024) {
    int i = base + t;
    int x = (i < NN) ? deg[i] : 0;
    int v = x;
#pragma unroll
    for (int d = 1; d < 64; d <<= 1) {
      int u = __shfl_up(v, d, 64);
      if (lane >= d) v += u;
    }
    if (lane == 63) waveSums[wv] = v;
    __syncthreads();
    if (wv == 0 && lane < 16) {
      int s = waveSums[lane];
#pragma unroll
      for (int d = 1; d < 16; d <<= 1) {
        int u = __shfl_up(s, d, 64);
        if (lane >= d) s += u;
      }
      waveSums[lane] = s;  // inclusive
    }
    __syncthreads();
    int waveOff = (wv == 0) ? 0 : waveSums[wv - 1];
    int incl = v + waveOff + sCarry;
    if (i < NN) prefix[i] = incl - x;  // exclusive
    __syncthreads();
    if (t == 1023) sCarry = incl;
    __syncthreads();
  }
  if (t == 0) prefix[NN] = sCarry;  // == EE
}

__global__ __launch_bounds__(256) void copy_cursor(
    const int* __restrict__ prefix, int* __restrict__ cursor) {
  int i = blockIdx.x * 256 + threadIdx.x;
  if (i < NN) cursor[i] = prefix[i];
}

__global__ __launch_bounds__(256) void scatter_kernel(
    const int* __restrict__ senders, const int* __restrict__ receivers,
    int* __restrict__ cursor, int2* __restrict__ sorted) {
  int e = blockIdx.x * 256 + threadIdx.x;
  if (e < EE) {
    int r = receivers[e];
    int pos = atomicAdd(&cursor[r], 1);
    sorted[pos] = make_int2(e, senders[e]);
  }
}

// ------------------- edge MLP: layers 1-2 VALU, layer 3 MFMA -------------------
// Block = 256 threads (4 waves), 64 sorted slots. Outputs mix (fp16) and y
// at SORTED positions -> gather reads are contiguous.
__global__ __launch_bounds__(256) void edge_mlp_mfma(
    const float* __restrict__ rbf, const float* __restrict__ vectors,
    const int2* __restrict__ sorted, const float* __restrict__ W1T_g,
    const float* __restrict__ W2T_g, const float* __restrict__ W3T_g,
    __half* __restrict__ mixH, float4* __restrict__ ybuf) {
  __shared__ float sW1[512];
  __shared__ float sW2[4096];
  __shared__ short sW3[192 * 64];  // bf16, [c][k], XOR-swizzled 8-elem chunks
  __shared__ short sH2[64 * 64];   // bf16, [slot][k], XOR-swizzled chunks

  int t = threadIdx.x;
  int pbase = blockIdx.x * 64;

  // stage weights
  for (int i = t; i < 512; i += 256) sW1[i] = W1T_g[i];
  for (int i = t; i < 4096; i += 256) sW2[i] = W2T_g[i];
  for (int i = t; i < 1536; i += 256) {  // (c, chunk-of-8)
    int c = i >> 3, ch = i & 7;
    const float* src = W3T_g + c * 64 + ch * 8;
    int4 pk;
    pk.x = ((unsigned)f2bf(src[1]) << 16) | (unsigned)f2bf(src[0]);
    pk.y = ((unsigned)f2bf(src[3]) << 16) | (unsigned)f2bf(src[2]);
    pk.z = ((unsigned)f2bf(src[5]) << 16) | (unsigned)f2bf(src[4]);
    pk.w = ((unsigned)f2bf(src[7]) << 16) | (unsigned)f2bf(src[6]);
    *(int4*)&sW3[c * 64 + ((ch ^ (c & 7)) << 3)] = pk;
  }

  int slot = t & 63;
  int q = t >> 6;  // wave id; wave q computes h2 channels [16q,16q+16)
  int p = pbase + slot;
  int2 es = sorted[p];
  int e = es.x;

  // y (wave 0 only)
  if (q == 0) {
    float vx = vectors[e * 3 + 0], vy = vectors[e * 3 + 1],
          vz = vectors[e * 3 + 2];
    float nrm = sqrtf(vx * vx + vy * vy + vz * vz) + 1e-12f;
    float ys = Y1C / nrm;
    ybuf[p] = make_float4(vx * ys, vy * ys, vz * ys, 0.f);
  }

  float4 ra = *(const float4*)(rbf + (size_t)e * 8);
  float4 rb = *(const float4*)(rbf + (size_t)e * 8 + 4);
  float r[8] = {ra.x, ra.y, ra.z, ra.w, rb.x, rb.y, rb.z, rb.w};

  __syncthreads();  // weights staged

  // layer 1 (full h1 per thread; weights wave-uniform LDS broadcast)
  float h1[64];
#pragma unroll
  for (int j = 0; j < 64; j++) {
    float4 w0 = *(const float4*)&sW1[j * 8];
    float4 w1 = *(const float4*)&sW1[j * 8 + 4];
    float a = r[0] * w0.x + r[1] * w0.y + r[2] * w0.z + r[3] * w0.w +
              r[4] * w1.x + r[5] * w1.y + r[6] * w1.z + r[7] * w1.w;
    h1[j] = silu(a);
  }
  // layer 2: this thread computes h2[slot][16q..16q+16)
  float h2v[16];
#pragma unroll
  for (int jj = 0; jj < 16; jj++) {
    int j = 16 * q + jj;
    float a = 0.f;
#pragma unroll
    for (int k = 0; k < 64; k += 4) {
      float4 w = *(const float4*)&sW2[j * 64 + k];
      a += h1[k] * w.x + h1[k + 1] * w.y + h1[k + 2] * w.z + h1[k + 3] * w.w;
    }
    h2v[jj] = silu(a);
  }
  // pack h2 -> LDS bf16 (A-fragment layout, swizzled)
  {
    int4 pk;
    pk.x = ((unsigned)f2bf(h2v[1]) << 16) | (unsigned)f2bf(h2v[0]);
    pk.y = ((unsigned)f2bf(h2v[3]) << 16) | (unsigned)f2bf(h2v[2]);
    pk.z = ((unsigned)f2bf(h2v[5]) << 16) | (unsigned)f2bf(h2v[4]);
    pk.w = ((unsigned)f2bf(h2v[7]) << 16) | (unsigned)f2bf(h2v[6]);
    *(int4*)&sH2[slot * 64 + (((2 * q) ^ (slot & 7)) << 3)] = pk;
    pk.x = ((unsigned)f2bf(h2v[9]) << 16) | (unsigned)f2bf(h2v[8]);
    pk.y = ((unsigned)f2bf(h2v[11]) << 16) | (unsigned)f2bf(h2v[10]);
    pk.z = ((unsigned)f2bf(h2v[13]) << 16) | (unsigned)f2bf(h2v[12]);
    pk.w = ((unsigned)f2bf(h2v[15]) << 16) | (unsigned)f2bf(h2v[14]);
    *(int4*)&sH2[slot * 64 + (((2 * q + 1) ^ (slot & 7)) << 3)] = pk;
  }
  __syncthreads();

  // layer 3 via MFMA 16x16x32 bf16. Wave w owns edge rows [16w,16w+16).
  int w = q;
  int lane = t & 63;
  int arow = 16 * w + (lane & 15);
  int kgrp = lane >> 4;
  short8 a0 = *(const short8*)&sH2[arow * 64 + ((kgrp ^ (arow & 7)) << 3)];
  short8 a1 = *(const short8*)&sH2[arow * 64 + (((4 + kgrp) ^ (arow & 7)) << 3)];

  int c = lane & 15;  // column within n-tile
#pragma unroll
  for (int nt = 0; nt < 12; nt++) {
    int cc = 16 * nt + c;
    short8 b0 = *(const short8*)&sW3[cc * 64 + ((kgrp ^ (cc & 7)) << 3)];
    short8 b1 = *(const short8*)&sW3[cc * 64 + (((4 + kgrp) ^ (cc & 7)) << 3)];
    f32x4 acc = {0.f, 0.f, 0.f, 0.f};
    acc = __builtin_amdgcn_mfma_f32_16x16x32_bf16(a0, b0, acc, 0, 0, 0);
    acc = __builtin_amdgcn_mfma_f32_16x16x32_bf16(a1, b1, acc, 0, 0, 0);
#pragma unroll
    for (int reg = 0; reg < 4; reg++) {
      int row = 16 * w + kgrp * 4 + reg;  // C/D: row=(lane>>4)*4+reg
      mixH[(size_t)(pbase + row) * 192 + cc] = __float2half_rn(acc[reg]);
    }
  }
}

// ------------------- gather (wave-per-edge) + down-proj + skip + gate -------------------
__global__ __launch_bounds__(384) void gather_out2(
    const float* __restrict__ nf, const int* __restrict__ species,
    const int2* __restrict__ sorted, const int* __restrict__ prefix,
    const float* __restrict__ s_up, const float* __restrict__ v_up,
    const __half* __restrict__ mixH, const float4* __restrict__ ybuf,
    const float* __restrict__ Wds, const float* __restrict__ Wdv,
    const float* __restrict__ Wss, const float* __restrict__ Wsv,
    float* __restrict__ out) {
  int n = blockIdx.x;
  int t = threadIdx.x;
  int w = t >> 6, lane = t & 63;
  __shared__ float sPart[6 * 384];
  __shared__ float sAgg[384];
  __shared__ float sNF[160];
  __shared__ float sF[224];

  if (t < 160) sNF[t] = nf[n * 160 + t];

  int beg = prefix[n], end = prefix[n + 1];
  int c0 = 6 * lane;  // this lane owns channels [c0, c0+6)
  float acc[6] = {0.f, 0.f, 0.f, 0.f, 0.f, 0.f};

  for (int it = beg + w; it < end; it += 6) {
    int snd = sorted[it].y;
    float4 y4 = ybuf[it];
    const unsigned* mp = (const unsigned*)(mixH + (size_t)it * 192);
    unsigned m01 = mp[3 * lane], m23 = mp[3 * lane + 1], m45 = mp[3 * lane + 2];
    float mx[6] = {h2f((unsigned short)(m01 & 0xFFFF)),
                   h2f((unsigned short)(m01 >> 16)),
                   h2f((unsigned short)(m23 & 0xFFFF)),
                   h2f((unsigned short)(m23 >> 16)),
                   h2f((unsigned short)(m45 & 0xFFFF)),
                   h2f((unsigned short)(m45 >> 16))};
    const float* se = s_up + (size_t)snd * 64;
    const float* ve = v_up + (size_t)snd * 96;
#pragma unroll
    for (int i = 0; i < 6; i++) {
      int ch = c0 + i;
      float b;
      if (ch < 64) {
        b = se[ch];
      } else if (ch < 96) {
        int cc = ch - 64;
        b = (ve[cc * 3] * y4.x + ve[cc * 3 + 1] * y4.y + ve[cc * 3 + 2] * y4.z) *
            INV_SQRT3;
      } else {
        int j = ch - 96;
        int cc = j / 3, ii = j - 3 * cc;
        float yv = (ii == 0) ? y4.x : ((ii == 1) ? y4.y : y4.z);
        b = (cc < 32) ? ve[cc * 3 + ii] : se[cc - 32] * yv;
      }
      acc[i] += b * mx[i];
    }
  }

#pragma unroll
  for (int i = 0; i < 6; i++) sPart[w * 384 + c0 + i] = acc[i];
  __syncthreads();
  {
    float s = 0.f;
#pragma unroll
    for (int w2 = 0; w2 < 6; w2++) s += sPart[w2 * 384 + t];
    sAgg[t] = s;
  }
  __syncthreads();

  int spec = species[n];
  if (t < 128) {
    float a = 0.f;
#pragma unroll
    for (int k = 0; k < 96; k++) a += sAgg[k] * Wds[k * 128 + t];
    a *= SC_DOWN;
    const float* wsk = Wss + spec * 64 * 128;
    float b = 0.f;
#pragma unroll
    for (int k = 0; k < 64; k++) b += sNF[k] * wsk[k * 128 + t];
    sF[t] = a + b * SC_SKIP_S;
  } else if (t < 224) {
    int jj = t - 128;
    int cc = jj / 3, i2 = jj - 3 * cc;
    float a = 0.f;
#pragma unroll
    for (int k = 0; k < 96; k++) a += sAgg[96 + k * 3 + i2] * Wdv[k * 32 + cc];
    a *= SC_DOWN;
    const float* wsk = Wsv + spec * 32 * 32;
    float b = 0.f;
#pragma unroll
    for (int k = 0; k < 32; k++) b += sNF[64 + k * 3 + i2] * wsk[k * 32 + cc];
    sF[128 + jj] = a + b * SC_SKIP_V;
  }
  __syncthreads();
  if (t < 96) {
    out[(size_t)n * 192 + t] = silu(sF[t]);
  } else if (t < 192) {
    int jj = t - 96;
    int cc = jj / 3;
    float g = silu(sF[96 + cc]);
    out[(size_t)n * 192 + jj + 96] = sF[128 + jj] * g;
  }
}

extern "C" void kernel_launch(void* const* d_in, const int* in_sizes, int n_in,
                              void* d_out, int out_size, void* d_ws, size_t ws_size,
                              hipStream_t stream) {
  const float* nf = (const float*)d_in[0];
  const float* vectors = (const float*)d_in[1];
  const float* rbf = (const float*)d_in[2];
  const int* species = (const int*)d_in[3];
  const int* senders = (const int*)d_in[4];
  const int* receivers = (const int*)d_in[5];
  const float* Wus = (const float*)d_in[6];
  const float* Wuv = (const float*)d_in[7];
  const float* W1 = (const float*)d_in[8];
  const float* W2 = (const float*)d_in[9];
  const float* W3 = (const float*)d_in[10];
  const float* Wds = (const float*)d_in[11];
  const float* Wdv = (const float*)d_in[12];
  const float* Wss = (const float*)d_in[13];
  const float* Wsv = (const float*)d_in[14];

  float* ws = (float*)d_ws;
  float* W1T = ws + W_W1T;
  float* W2T = ws + W_W2T;
  float* W3T = ws + W_W3T;
  float* s_up = ws + W_SUP;
  float* v_up = ws + W_VUP;
  float4* ybuf = (float4*)(ws + W_Y);
  __half* mixH = (__half*)(ws + W_MIX);
  int* deg = (int*)(ws + W_DEG);
  int* prefix = (int*)(ws + W_PRE);
  int* cursor = (int*)(ws + W_CUR);
  int2* sorted = (int2*)(ws + W_SRT);
  float* out = (float*)d_out;

  transpose_weights<<<16, 256, 0, stream>>>(W1, W2, W3, ws);
  up_kernel<<<NN, 256, 0, stream>>>(nf, Wus, Wuv, s_up, v_up);

  hipMemsetAsync(deg, 0, (size_t)NN * sizeof(int), stream);
  count_deg<<<(EE + 255) / 256, 256, 0, stream>>>(receivers, deg);
  scan_kernel<<<1, 1024, 0, stream>>>(deg, prefix);
  copy_cursor<<<(NN + 255) / 256, 256, 0, stream>>>(prefix, cursor);
  scatter_kernel<<<(EE + 255) / 256, 256, 0, stream>>>(senders, receivers,
                                                       cursor, sorted);
  edge_mlp_mfma<<<EE / 64, 256, 0, stream>>>(rbf, vectors, sorted, W1T, W2T,
                                             W3T, mixH, ybuf);
  gather_out2<<<NN, 384, 0, stream>>>(nf, species, sorted, prefix, s_up, v_up,
                                      mixH, ybuf, Wds, Wdv, Wss, Wsv, out);
}

// Round 6
// 477.039 us; speedup vs baseline: 17.4411x; 2.0467x over previous
//
#include <hip/hip_runtime.h>
#include <hip/hip_bf16.h>
#include <hip/hip_fp16.h>
#include <hip/hip_fp8.h>

#define NN 25000
#define EE 400000

#define SC_UP_S 0.125f
#define SC_UP_V 0.17677669529663689f
#define Y1C 0.48860251190291992f
#define SC_MLP1 0.35355339059327373f
#define SC_MLP2 0.125f
#define SC3 0.0013020833333333333f      // (1/8)*(1/96) folded into W3
#define INV_SQRT3 0.57735026918962584f
#define SC_DOWN 0.025515518153991442f   // (1/4)*(1/sqrt(96)) folded into Wd
#define SC_SKIP_S 0.125f
#define SC_SKIP_V 0.17677669529663689f

typedef __attribute__((ext_vector_type(8))) short short8;
typedef __attribute__((ext_vector_type(4))) float f32x4;

__device__ __forceinline__ float silu(float x) {
  return __fdividef(x, 1.f + __expf(-x));
}
__device__ __forceinline__ unsigned short f2bf(float f) {
  unsigned u = __float_as_uint(f);
  unsigned r = u + 0x7FFF + ((u >> 16) & 1);
  return (unsigned short)(r >> 16);
}
__device__ __forceinline__ float bf2f(unsigned short s) {
  return __uint_as_float(((unsigned)s) << 16);
}
__device__ __forceinline__ unsigned packbf(float lo, float hi) {
  return ((unsigned)f2bf(hi) << 16) | (unsigned)f2bf(lo);
}
__device__ __forceinline__ unsigned char f2fp8(float x) {
  __hip_fp8_e4m3 v(x);
  return (unsigned char)v.__x;
}
__device__ __forceinline__ float fp82f(unsigned b) {
  __hip_fp8_e4m3 t;
  t.__x = (__hip_fp8_storage_t)b;
  return (float)t;
}

// ---------------- workspace layout (4-byte word offsets) ----------------
#define W_W1T 0
#define W_W2T 512
#define W_W3B 4608                     // 12288 bf16 = 6144 words
#define W_WDS 10752                    // 12288 bf16
#define W_WDV 16896                    // 3072 bf16 = 1536 words
#define W_SUP 18432
#define W_VUP (W_SUP + NN * 64)
#define W_DEG (W_VUP + NN * 96)
#define W_PRE (W_DEG + NN)
#define W_CUR (W_PRE + NN + 8)
#define W_SRT (W_CUR + NN)             // int2 per slot (even offset)
#define W_EDN (W_SRT + EE * 2)         // fp8: EE*224 bytes = EE*56 words
#define W_END (W_EDN + EE * 56)        // ~109.2 MB (<= 179.7 MB proven)

// ---------------- setup: weight transforms ----------------
__global__ __launch_bounds__(256) void transpose_weights(
    const float* __restrict__ W1, const float* __restrict__ W2,
    const float* __restrict__ W3, const float* __restrict__ Wds,
    const float* __restrict__ Wdv, float* __restrict__ ws) {
  int t = blockIdx.x * 256 + threadIdx.x;
  int stride = gridDim.x * 256;
  unsigned short* W3b = (unsigned short*)(ws + W_W3B);
  unsigned short* Wdsb = (unsigned short*)(ws + W_WDS);
  unsigned short* Wdvb = (unsigned short*)(ws + W_WDV);
  for (int i = t; i < 512; i += stride) {   // W1T[j*8+k]
    int j = i >> 3, k = i & 7;
    ws[W_W1T + i] = W1[k * 64 + j] * SC_MLP1;
  }
  for (int i = t; i < 4096; i += stride) {  // W2T[j*64+k]
    int j = i >> 6, k = i & 63;
    ws[W_W2T + i] = W2[k * 64 + j] * SC_MLP2;
  }
  for (int i = t; i < 12288; i += stride) { // W3b[c*64+k]
    int c = i >> 6, k = i & 63;
    W3b[i] = f2bf(W3[k * 192 + c] * SC3);
  }
  for (int i = t; i < 12288; i += stride) { // Wdsb[o*96+k], o<128,k<96
    int o = i / 96, k = i - 96 * o;
    Wdsb[i] = f2bf(Wds[k * 128 + o] * SC_DOWN);
  }
  for (int i = t; i < 3072; i += stride) {  // Wdvb[o*96+k], o<32,k<96
    int o = i / 96, k = i - 96 * o;
    Wdvb[i] = f2bf(Wdv[k * 32 + o] * SC_DOWN);
  }
}

// ---------------- per-node up-projection (fp32) ----------------
__global__ __launch_bounds__(256) void up_kernel(
    const float* __restrict__ nf, const float* __restrict__ Wus,
    const float* __restrict__ Wuv, float* __restrict__ s_up,
    float* __restrict__ v_up) {
  int n = blockIdx.x;
  int t = threadIdx.x;
  __shared__ float sv[160];
  if (t < 160) sv[t] = nf[n * 160 + t];
  __syncthreads();
  if (t < 64) {
    float a = 0.f;
#pragma unroll
    for (int k = 0; k < 64; k++) a += sv[k] * Wus[k * 64 + t];
    s_up[n * 64 + t] = a * SC_UP_S;
  } else if (t < 160) {
    int j = t - 64;
    int c = j / 3, i = j - 3 * c;
    float a = 0.f;
#pragma unroll
    for (int k = 0; k < 32; k++) a += sv[64 + k * 3 + i] * Wuv[k * 32 + c];
    v_up[n * 96 + j] = a * SC_UP_V;
  }
}

// ---------------- counting sort by receiver ----------------
__global__ __launch_bounds__(256) void count_deg(
    const int* __restrict__ receivers, int* __restrict__ deg) {
  int e = blockIdx.x * 256 + threadIdx.x;
  if (e < EE) atomicAdd(&deg[receivers[e]], 1);
}

__global__ __launch_bounds__(1024) void scan_kernel(
    const int* __restrict__ deg, int* __restrict__ prefix) {
  __shared__ int waveSums[16];
  __shared__ int sCarry;
  int t = threadIdx.x;
  int lane = t & 63, wv = t >> 6;
  if (t == 0) sCarry = 0;
  __syncthreads();
  for (int base = 0; base < NN; base += 1024) {
    int i = base + t;
    int x = (i < NN) ? deg[i] : 0;
    int v = x;
#pragma unroll
    for (int d = 1; d < 64; d <<= 1) {
      int u = __shfl_up(v, d, 64);
      if (lane >= d) v += u;
    }
    if (lane == 63) waveSums[wv] = v;
    __syncthreads();
    if (wv == 0 && lane < 16) {
      int s = waveSums[lane];
#pragma unroll
      for (int d = 1; d < 16; d <<= 1) {
        int u = __shfl_up(s, d, 64);
        if (lane >= d) s += u;
      }
      waveSums[lane] = s;
    }
    __syncthreads();
    int waveOff = (wv == 0) ? 0 : waveSums[wv - 1];
    int incl = v + waveOff + sCarry;
    if (i < NN) prefix[i] = incl - x;
    __syncthreads();
    if (t == 1023) sCarry = incl;
    __syncthreads();
  }
  if (t == 0) prefix[NN] = sCarry;
}

__global__ __launch_bounds__(256) void copy_cursor(
    const int* __restrict__ prefix, int* __restrict__ cursor) {
  int i = blockIdx.x * 256 + threadIdx.x;
  if (i < NN) cursor[i] = prefix[i];
}

__global__ __launch_bounds__(256) void scatter_kernel(
    const int* __restrict__ senders, const int* __restrict__ receivers,
    int* __restrict__ cursor, int2* __restrict__ sorted) {
  int e = blockIdx.x * 256 + threadIdx.x;
  if (e < EE) {
    int r = receivers[e];
    int pos = atomicAdd(&cursor[r], 1);
    sorted[pos] = make_int2(e, senders[e]);
  }
}

// ---------------- fused edge MLP + message + down-projection ----------------
// Block = 256 threads (4 waves) handles 64 sorted slots.
// Phases: stage/y -> l1,l2 (VALU) -> l3 (MFMA, mix->LDS) -> msg build (LDS bf16)
//         -> down-proj (MFMA) -> edown fp8 global (sorted order).
__global__ __launch_bounds__(256, 2) void edge_down(
    const float* __restrict__ rbf, const float* __restrict__ vectors,
    const int2* __restrict__ sorted, const float* __restrict__ W1T_g,
    const float* __restrict__ W2T_g, const unsigned short* __restrict__ W3b,
    const unsigned short* __restrict__ Wdsb,
    const unsigned short* __restrict__ Wdvb,
    const float* __restrict__ s_up, const float* __restrict__ v_up,
    unsigned char* __restrict__ edown) {
  __shared__ char smem[79104];
  unsigned short* sMsgS = (unsigned short*)smem;            // [64][104] bf16
  unsigned short* sMsgV0 = (unsigned short*)(smem + 13312); // [64][104]
  unsigned short* sMsgV1 = (unsigned short*)(smem + 26624);
  unsigned short* sMsgV2 = (unsigned short*)(smem + 39936);
  unsigned short* sMix = (unsigned short*)(smem + 53248);   // [64][194] bf16
  float4* sY = (float4*)(smem + 78080);                     // [64]
  // aliases (dead before msg build overwrites them)
  float* sW1 = (float*)smem;                 // [512]
  float* sW2 = (float*)(smem + 2048);        // [4096]
  unsigned short* sH2 = (unsigned short*)(smem + 18432);  // [64][72] bf16

  int t = threadIdx.x;
  int pbase = blockIdx.x * 64;
  int lane = t & 63;
  int wv = t >> 6;

  // ---- phase 0: y + weight staging ----
  if (t < 64) {
    int2 es = sorted[pbase + t];
    float vx = vectors[(size_t)es.x * 3 + 0];
    float vy = vectors[(size_t)es.x * 3 + 1];
    float vz = vectors[(size_t)es.x * 3 + 2];
    float nrm = sqrtf(vx * vx + vy * vy + vz * vz) + 1e-12f;
    float ysc = Y1C / nrm;
    sY[t] = make_float4(vx * ysc, vy * ysc, vz * ysc, __int_as_float(es.y));
  }
  for (int i = t; i < 512; i += 256) sW1[i] = W1T_g[i];
  for (int i = t; i < 4096; i += 256) sW2[i] = W2T_g[i];
  int eid = sorted[pbase + lane].x;
  float4 ra = *(const float4*)(rbf + (size_t)eid * 8);
  float4 rb = *(const float4*)(rbf + (size_t)eid * 8 + 4);
  __syncthreads();

  // ---- phase 1: l1 (redundant x4) + l2 (wave-sliced), slot = lane ----
  float r0_[8] = {ra.x, ra.y, ra.z, ra.w, rb.x, rb.y, rb.z, rb.w};
  float h1[64];
#pragma unroll
  for (int j = 0; j < 64; j++) {
    float4 w0 = *(const float4*)&sW1[j * 8];
    float4 w1 = *(const float4*)&sW1[j * 8 + 4];
    float a = r0_[0] * w0.x + r0_[1] * w0.y + r0_[2] * w0.z + r0_[3] * w0.w +
              r0_[4] * w1.x + r0_[5] * w1.y + r0_[6] * w1.z + r0_[7] * w1.w;
    h1[j] = silu(a);
  }
  float h2v[16];
#pragma unroll
  for (int jj = 0; jj < 16; jj++) {
    int j = 16 * wv + jj;
    float a = 0.f;
#pragma unroll
    for (int k = 0; k < 64; k += 4) {
      float4 w = *(const float4*)&sW2[j * 64 + k];
      a += h1[k] * w.x + h1[k + 1] * w.y + h1[k + 2] * w.z + h1[k + 3] * w.w;
    }
    h2v[jj] = silu(a);
  }
  {
    int4 pk;
    pk.x = packbf(h2v[0], h2v[1]);
    pk.y = packbf(h2v[2], h2v[3]);
    pk.z = packbf(h2v[4], h2v[5]);
    pk.w = packbf(h2v[6], h2v[7]);
    *(int4*)&sH2[lane * 72 + 16 * wv] = pk;
    pk.x = packbf(h2v[8], h2v[9]);
    pk.y = packbf(h2v[10], h2v[11]);
    pk.z = packbf(h2v[12], h2v[13]);
    pk.w = packbf(h2v[14], h2v[15]);
    *(int4*)&sH2[lane * 72 + 16 * wv + 8] = pk;
  }
  __syncthreads();

  // ---- phase 2: l3 MFMA, wave wv owns rows [16wv, 16wv+16) ----
  int kgrp = lane >> 4;
  int rl = lane & 15;
  int arow = 16 * wv + rl;
  {
    short8 a0 = *(const short8*)&sH2[arow * 72 + kgrp * 8];
    short8 a1 = *(const short8*)&sH2[arow * 72 + 32 + kgrp * 8];
#pragma unroll
    for (int nt = 0; nt < 12; nt++) {
      int cc = nt * 16 + rl;
      short8 b0 = *(const short8*)&W3b[cc * 64 + kgrp * 8];
      short8 b1 = *(const short8*)&W3b[cc * 64 + 32 + kgrp * 8];
      f32x4 acc = {0.f, 0.f, 0.f, 0.f};
      acc = __builtin_amdgcn_mfma_f32_16x16x32_bf16(a0, b0, acc, 0, 0, 0);
      acc = __builtin_amdgcn_mfma_f32_16x16x32_bf16(a1, b1, acc, 0, 0, 0);
#pragma unroll
      for (int rr = 0; rr < 4; rr++) {
        int row = 16 * wv + kgrp * 4 + rr;
        sMix[row * 194 + cc] = f2bf(acc[rr]);
      }
    }
  }
  __syncthreads();

  // ---- phase 3: msg build. slot = t>>2, sub = t&3 owns k-slices ----
  {
    int slot = t >> 2, sub = t & 3;
    float4 yv = sY[slot];
    int snd = __float_as_int(yv.w);
    const float* se = s_up + (size_t)snd * 64 + 16 * sub;
    const float* ve = v_up + (size_t)snd * 96 + 24 * sub;
    float se16[16], ve24[24];
#pragma unroll
    for (int j = 0; j < 4; j++) *(float4*)&se16[4 * j] = *(const float4*)&se[4 * j];
#pragma unroll
    for (int j = 0; j < 6; j++) *(float4*)&ve24[4 * j] = *(const float4*)&ve[4 * j];
    const unsigned short* mixr = sMix + slot * 194;
    unsigned short* ms = sMsgS + slot * 104;
    // msg_s channels [16sub, 16sub+16): s_e * mix
#pragma unroll
    for (int j = 0; j < 16; j += 2) {
      int k = 16 * sub + j;
      *(unsigned*)&ms[k] = packbf(se16[j] * bf2f(mixr[k]),
                                  se16[j + 1] * bf2f(mixr[k + 1]));
    }
    // msg_s channels [64+8sub, 64+8sub+8): tp_s * mix
#pragma unroll
    for (int j = 0; j < 8; j += 2) {
      int c = 8 * sub + j;
      float t0 = (ve24[3 * j] * yv.x + ve24[3 * j + 1] * yv.y +
                  ve24[3 * j + 2] * yv.z) * INV_SQRT3;
      float t1 = (ve24[3 * j + 3] * yv.x + ve24[3 * j + 4] * yv.y +
                  ve24[3 * j + 5] * yv.z) * INV_SQRT3;
      *(unsigned*)&ms[64 + c] = packbf(t0 * bf2f(mixr[64 + c]),
                                       t1 * bf2f(mixr[64 + c + 1]));
    }
    // msg_v components
#pragma unroll
    for (int i = 0; i < 3; i++) {
      unsigned short* mv =
          (i == 0 ? sMsgV0 : (i == 1 ? sMsgV1 : sMsgV2)) + slot * 104;
      float yi = (i == 0) ? yv.x : ((i == 1) ? yv.y : yv.z);
      // channels [8sub, 8sub+8): v_e[c][i] * mixv[c]
#pragma unroll
      for (int j = 0; j < 8; j += 2) {
        int c = 8 * sub + j;
        *(unsigned*)&mv[c] = packbf(ve24[3 * j + i] * bf2f(mixr[96 + c]),
                                    ve24[3 * (j + 1) + i] * bf2f(mixr[96 + c + 1]));
      }
      // channels [32+16sub, 32+16sub+16): s_e[c-32]*y_i*mixv[c]
#pragma unroll
      for (int j = 0; j < 16; j += 2) {
        int c = 32 + 16 * sub + j;
        *(unsigned*)&mv[c] = packbf(se16[j] * yi * bf2f(mixr[96 + c]),
                                    se16[j + 1] * yi * bf2f(mixr[96 + c + 1]));
      }
    }
  }
  __syncthreads();

  // ---- phase 4: down-proj MFMA -> edown fp8 ----
  // scalar: [64x96] @ [96x128]
  {
    short8 as0 = *(const short8*)&sMsgS[arow * 104 + kgrp * 8];
    short8 as1 = *(const short8*)&sMsgS[arow * 104 + 32 + kgrp * 8];
    short8 as2 = *(const short8*)&sMsgS[arow * 104 + 64 + kgrp * 8];
#pragma unroll
    for (int ot = 0; ot < 8; ot++) {
      int col = 16 * ot + rl;
      short8 b0 = *(const short8*)&Wdsb[col * 96 + kgrp * 8];
      short8 b1 = *(const short8*)&Wdsb[col * 96 + 32 + kgrp * 8];
      short8 b2 = *(const short8*)&Wdsb[col * 96 + 64 + kgrp * 8];
      f32x4 acc = {0.f, 0.f, 0.f, 0.f};
      acc = __builtin_amdgcn_mfma_f32_16x16x32_bf16(as0, b0, acc, 0, 0, 0);
      acc = __builtin_amdgcn_mfma_f32_16x16x32_bf16(as1, b1, acc, 0, 0, 0);
      acc = __builtin_amdgcn_mfma_f32_16x16x32_bf16(as2, b2, acc, 0, 0, 0);
#pragma unroll
      for (int rr = 0; rr < 4; rr++) {
        int row = pbase + 16 * wv + kgrp * 4 + rr;
        edown[(size_t)row * 224 + col] = f2fp8(acc[rr]);
      }
    }
  }
  // vector comps: [64x96] @ [96x32] each
#pragma unroll
  for (int i = 0; i < 3; i++) {
    const unsigned short* mv =
        (i == 0 ? sMsgV0 : (i == 1 ? sMsgV1 : sMsgV2));
    short8 av0 = *(const short8*)&mv[arow * 104 + kgrp * 8];
    short8 av1 = *(const short8*)&mv[arow * 104 + 32 + kgrp * 8];
    short8 av2 = *(const short8*)&mv[arow * 104 + 64 + kgrp * 8];
#pragma unroll
    for (int ot = 0; ot < 2; ot++) {
      int o = 16 * ot + rl;
      short8 b0 = *(const short8*)&Wdvb[o * 96 + kgrp * 8];
      short8 b1 = *(const short8*)&Wdvb[o * 96 + 32 + kgrp * 8];
      short8 b2 = *(const short8*)&Wdvb[o * 96 + 64 + kgrp * 8];
      f32x4 acc = {0.f, 0.f, 0.f, 0.f};
      acc = __builtin_amdgcn_mfma_f32_16x16x32_bf16(av0, b0, acc, 0, 0, 0);
      acc = __builtin_amdgcn_mfma_f32_16x16x32_bf16(av1, b1, acc, 0, 0, 0);
      acc = __builtin_amdgcn_mfma_f32_16x16x32_bf16(av2, b2, acc, 0, 0, 0);
#pragma unroll
      for (int rr = 0; rr < 4; rr++) {
        int row = pbase + 16 * wv + kgrp * 4 + rr;
        edown[(size_t)row * 224 + 128 + o * 3 + i] = f2fp8(acc[rr]);
      }
    }
  }
}

// ---------------- gather: streaming segmented sum + skip + gate ----------------
__global__ __launch_bounds__(256) void gather_out3(
    const float* __restrict__ nf, const int* __restrict__ species,
    const int* __restrict__ prefix, const unsigned* __restrict__ edw,
    const float* __restrict__ Wss, const float* __restrict__ Wsv,
    float* __restrict__ out) {
  int n = blockIdx.x;
  int t = threadIdx.x;
  __shared__ float sNF[160];
  __shared__ float4 sPart[4][56];
  __shared__ float sEd[224];
  __shared__ float sF[224];
  if (t < 160) sNF[t] = nf[(size_t)n * 160 + t];
  int beg = prefix[n], end = prefix[n + 1];
  if (t < 224) {
    int u = t % 56, rg = t / 56;
    float a0 = 0.f, a1 = 0.f, a2 = 0.f, a3 = 0.f;
    for (int s = beg + rg; s < end; s += 4) {
      unsigned v = edw[(size_t)s * 56 + u];
      a0 += fp82f(v & 0xFF);
      a1 += fp82f((v >> 8) & 0xFF);
      a2 += fp82f((v >> 16) & 0xFF);
      a3 += fp82f(v >> 24);
    }
    sPart[rg][u] = make_float4(a0, a1, a2, a3);
  }
  __syncthreads();
  if (t < 56) {
    float4 a = sPart[0][t], b = sPart[1][t], c = sPart[2][t], d = sPart[3][t];
    sEd[4 * t + 0] = a.x + b.x + c.x + d.x;
    sEd[4 * t + 1] = a.y + b.y + c.y + d.y;
    sEd[4 * t + 2] = a.z + b.z + c.z + d.z;
    sEd[4 * t + 3] = a.w + b.w + c.w + d.w;
  }
  __syncthreads();
  int spec = species[n];
  if (t < 128) {
    const float* wsk = Wss + (size_t)spec * 64 * 128;
    float b = 0.f;
#pragma unroll
    for (int k = 0; k < 64; k++) b += sNF[k] * wsk[k * 128 + t];
    sF[t] = sEd[t] + b * SC_SKIP_S;
  } else if (t < 224) {
    int j = t - 128;
    int c = j / 3, i = j - 3 * c;
    const float* wsk = Wsv + (size_t)spec * 32 * 32;
    float b = 0.f;
#pragma unroll
    for (int k = 0; k < 32; k++) b += sNF[64 + k * 3 + i] * wsk[k * 32 + c];
    sF[t] = sEd[t] + b * SC_SKIP_V;
  }
  __syncthreads();
  if (t < 96) {
    out[(size_t)n * 192 + t] = silu(sF[t]);
  } else if (t < 192) {
    int j = t - 96;
    int c = j / 3;
    out[(size_t)n * 192 + t] = sF[128 + j] * silu(sF[96 + c]);
  }
}

extern "C" void kernel_launch(void* const* d_in, const int* in_sizes, int n_in,
                              void* d_out, int out_size, void* d_ws, size_t ws_size,
                              hipStream_t stream) {
  const float* nf = (const float*)d_in[0];
  const float* vectors = (const float*)d_in[1];
  const float* rbf = (const float*)d_in[2];
  const int* species = (const int*)d_in[3];
  const int* senders = (const int*)d_in[4];
  const int* receivers = (const int*)d_in[5];
  const float* Wus = (const float*)d_in[6];
  const float* Wuv = (const float*)d_in[7];
  const float* W1 = (const float*)d_in[8];
  const float* W2 = (const float*)d_in[9];
  const float* W3 = (const float*)d_in[10];
  const float* Wds = (const float*)d_in[11];
  const float* Wdv = (const float*)d_in[12];
  const float* Wss = (const float*)d_in[13];
  const float* Wsv = (const float*)d_in[14];

  float* ws = (float*)d_ws;
  float* W1T = ws + W_W1T;
  float* W2T = ws + W_W2T;
  const unsigned short* W3b = (const unsigned short*)(ws + W_W3B);
  const unsigned short* Wdsb = (const unsigned short*)(ws + W_WDS);
  const unsigned short* Wdvb = (const unsigned short*)(ws + W_WDV);
  float* s_up = ws + W_SUP;
  float* v_up = ws + W_VUP;
  int* deg = (int*)(ws + W_DEG);
  int* prefix = (int*)(ws + W_PRE);
  int* cursor = (int*)(ws + W_CUR);
  int2* sorted = (int2*)(ws + W_SRT);
  unsigned char* edown = (unsigned char*)(ws + W_EDN);
  float* out = (float*)d_out;

  transpose_weights<<<16, 256, 0, stream>>>(W1, W2, W3, Wds, Wdv, ws);
  up_kernel<<<NN, 256, 0, stream>>>(nf, Wus, Wuv, s_up, v_up);

  hipMemsetAsync(deg, 0, (size_t)NN * sizeof(int), stream);
  count_deg<<<(EE + 255) / 256, 256, 0, stream>>>(receivers, deg);
  scan_kernel<<<1, 1024, 0, stream>>>(deg, prefix);
  copy_cursor<<<(NN + 255) / 256, 256, 0, stream>>>(prefix, cursor);
  scatter_kernel<<<(EE + 255) / 256, 256, 0, stream>>>(senders, receivers,
                                                       cursor, sorted);
  edge_down<<<EE / 64, 256, 0, stream>>>(rbf, vectors, sorted, W1T, W2T, W3b,
                                         Wdsb, Wdvb, s_up, v_up, edown);
  gather_out3<<<NN, 256, 0, stream>>>(nf, species, prefix, (const unsigned*)edown,
                                      Wss, Wsv, out);
}

// Round 7
// 375.042 us; speedup vs baseline: 22.1844x; 1.2720x over previous
//
#include <hip/hip_runtime.h>
#include <hip/hip_bf16.h>
#include <hip/hip_fp16.h>
#include <hip/hip_fp8.h>

#define NN 25000
#define EE 400000

#define SC_UP_S 0.125f
#define SC_UP_V 0.17677669529663689f
#define Y1C 0.48860251190291992f
#define SC_MLP1 0.35355339059327373f
#define SC_MLP2 0.125f
#define SC3 0.0013020833333333333f      // (1/8)*(1/96) folded into W3
#define INV_SQRT3 0.57735026918962584f  // folded into W3 cols 64..96
#define SC_DOWN 0.025515518153991442f   // (1/4)*(1/sqrt(96)) folded into Wd
#define SC_SKIP_S 0.125f
#define SC_SKIP_V 0.17677669529663689f

typedef __attribute__((ext_vector_type(8))) short short8;
typedef __attribute__((ext_vector_type(4))) float f32x4;

__device__ __forceinline__ float silu(float x) {
  return __fdividef(x, 1.f + __expf(-x));
}
__device__ __forceinline__ unsigned short f2bf(float f) {
  unsigned u = __float_as_uint(f);
  unsigned r = u + 0x7FFF + ((u >> 16) & 1);
  return (unsigned short)(r >> 16);
}
__device__ __forceinline__ float bf2f(unsigned short s) {
  return __uint_as_float(((unsigned)s) << 16);
}
__device__ __forceinline__ unsigned packbf(float lo, float hi) {
  return ((unsigned)f2bf(hi) << 16) | (unsigned)f2bf(lo);
}
__device__ __forceinline__ unsigned char f2fp8(float x) {
  __hip_fp8_e4m3 v(x);
  return (unsigned char)v.__x;
}
__device__ __forceinline__ float fp82f(unsigned b) {
  __hip_fp8_e4m3 t;
  t.__x = (__hip_fp8_storage_t)b;
  return (float)t;
}

// ---------------- workspace layout (4-byte word offsets) ----------------
#define W_W1P 0                        // 64x32 bf16 (K zero-padded 8->32)
#define W_W2P 1024                     // 64x64 bf16 [col][k]
#define W_W3B 3072                     // 192x64 bf16 [col][k]
#define W_WDS 9216                     // 128x96 bf16 [col][k]
#define W_WDV 15360                    // 32x96 bf16 [col][k]
#define W_SUP 16896
#define W_VUP (W_SUP + NN * 64)
#define W_DEG (W_VUP + NN * 96)
#define W_PRE (W_DEG + NN)
#define W_CUR (W_PRE + NN + 8)
#define W_SRT (W_CUR + NN)             // int2 per slot (even offset)
#define W_EDN (W_SRT + EE * 2)         // fp8: EE*224 bytes = EE*56 words
#define W_END (W_EDN + EE * 56)        // ~109.2 MB

// ---------------- setup: weight transforms ----------------
__global__ __launch_bounds__(256) void transpose_weights(
    const float* __restrict__ W1, const float* __restrict__ W2,
    const float* __restrict__ W3, const float* __restrict__ Wds,
    const float* __restrict__ Wdv, float* __restrict__ ws) {
  int t = blockIdx.x * 256 + threadIdx.x;
  int stride = gridDim.x * 256;
  unsigned short* W1p = (unsigned short*)(ws + W_W1P);
  unsigned short* W2p = (unsigned short*)(ws + W_W2P);
  unsigned short* W3b = (unsigned short*)(ws + W_W3B);
  unsigned short* Wdsb = (unsigned short*)(ws + W_WDS);
  unsigned short* Wdvb = (unsigned short*)(ws + W_WDV);
  for (int i = t; i < 2048; i += stride) {  // W1p[c*32+k], k<8 real
    int c = i >> 5, k = i & 31;
    W1p[i] = (k < 8) ? f2bf(W1[k * 64 + c] * SC_MLP1) : (unsigned short)0;
  }
  for (int i = t; i < 4096; i += stride) {  // W2p[c*64+k]
    int c = i >> 6, k = i & 63;
    W2p[i] = f2bf(W2[k * 64 + c] * SC_MLP2);
  }
  for (int i = t; i < 12288; i += stride) { // W3b[c*64+k]; 1/sqrt3 fold c in [64,96)
    int c = i >> 6, k = i & 63;
    float sc = (c >= 64 && c < 96) ? (SC3 * INV_SQRT3) : SC3;
    W3b[i] = f2bf(W3[k * 192 + c] * sc);
  }
  for (int i = t; i < 12288; i += stride) { // Wdsb[o*96+k]
    int o = i / 96, k = i - 96 * o;
    Wdsb[i] = f2bf(Wds[k * 128 + o] * SC_DOWN);
  }
  for (int i = t; i < 3072; i += stride) {  // Wdvb[o*96+k]
    int o = i / 96, k = i - 96 * o;
    Wdvb[i] = f2bf(Wdv[k * 32 + o] * SC_DOWN);
  }
}

// ---------------- per-node up-projection (fp32) ----------------
__global__ __launch_bounds__(256) void up_kernel(
    const float* __restrict__ nf, const float* __restrict__ Wus,
    const float* __restrict__ Wuv, float* __restrict__ s_up,
    float* __restrict__ v_up) {
  int n = blockIdx.x;
  int t = threadIdx.x;
  __shared__ float sv[160];
  if (t < 160) sv[t] = nf[n * 160 + t];
  __syncthreads();
  if (t < 64) {
    float a = 0.f;
#pragma unroll
    for (int k = 0; k < 64; k++) a += sv[k] * Wus[k * 64 + t];
    s_up[n * 64 + t] = a * SC_UP_S;
  } else if (t < 160) {
    int j = t - 64;
    int c = j / 3, i = j - 3 * c;
    float a = 0.f;
#pragma unroll
    for (int k = 0; k < 32; k++) a += sv[64 + k * 3 + i] * Wuv[k * 32 + c];
    v_up[n * 96 + j] = a * SC_UP_V;
  }
}

// ---------------- counting sort by receiver ----------------
__global__ __launch_bounds__(256) void count_deg(
    const int* __restrict__ receivers, int* __restrict__ deg) {
  int e = blockIdx.x * 256 + threadIdx.x;
  if (e < EE) atomicAdd(&deg[receivers[e]], 1);
}

__global__ __launch_bounds__(1024) void scan_kernel(
    const int* __restrict__ deg, int* __restrict__ prefix) {
  __shared__ int waveSums[16];
  __shared__ int sCarry;
  int t = threadIdx.x;
  int lane = t & 63, wv = t >> 6;
  if (t == 0) sCarry = 0;
  __syncthreads();
  for (int base = 0; base < NN; base += 1024) {
    int i = base + t;
    int x = (i < NN) ? deg[i] : 0;
    int v = x;
#pragma unroll
    for (int d = 1; d < 64; d <<= 1) {
      int u = __shfl_up(v, d, 64);
      if (lane >= d) v += u;
    }
    if (lane == 63) waveSums[wv] = v;
    __syncthreads();
    if (wv == 0 && lane < 16) {
      int s = waveSums[lane];
#pragma unroll
      for (int d = 1; d < 16; d <<= 1) {
        int u = __shfl_up(s, d, 64);
        if (lane >= d) s += u;
      }
      waveSums[lane] = s;
    }
    __syncthreads();
    int waveOff = (wv == 0) ? 0 : waveSums[wv - 1];
    int incl = v + waveOff + sCarry;
    if (i < NN) prefix[i] = incl - x;
    __syncthreads();
    if (t == 1023) sCarry = incl;
    __syncthreads();
  }
  if (t == 0) prefix[NN] = sCarry;
}

__global__ __launch_bounds__(256) void copy_cursor(
    const int* __restrict__ prefix, int* __restrict__ cursor) {
  int i = blockIdx.x * 256 + threadIdx.x;
  if (i < NN) cursor[i] = prefix[i];
}

__global__ __launch_bounds__(256) void scatter_kernel(
    const int* __restrict__ senders, const int* __restrict__ receivers,
    int* __restrict__ cursor, int2* __restrict__ sorted) {
  int e = blockIdx.x * 256 + threadIdx.x;
  if (e < EE) {
    int r = receivers[e];
    int pos = atomicAdd(&cursor[r], 1);
    sorted[pos] = make_int2(e, senders[e]);
  }
}

// ---------------- fused edge pipeline, all-MFMA ----------------
// Block = 256 thr / 4 waves / 64 edges. Wave w owns rows [16w,16w+16) of every
// LDS buffer -> all LDS traffic is wave-private (3 barriers total).
// l1: h1 = silu(rbf@W1)  [64x8 -> 64x64]   MFMA (K zero-padded)
// l2: h2 = silu(h1@W2)   [64x64 -> 64x64]  MFMA
// l3: mix = h2@W3        [64x64 -> 64x192] MFMA -> sMix (bf16)
// ph3: A-fragments of msg (per-lane, registers; global se/ve gather)
// ph4: edown = msg@Wd    MFMA -> fp8 -> LDS stage -> coalesced copy-out
__global__ __launch_bounds__(256, 4) void edge_down2(
    const float* __restrict__ rbf, const float* __restrict__ vectors,
    const int2* __restrict__ sorted,
    const unsigned short* __restrict__ W1p,
    const unsigned short* __restrict__ W2p,
    const unsigned short* __restrict__ W3b,
    const unsigned short* __restrict__ Wdsb,
    const unsigned short* __restrict__ Wdvb,
    const float* __restrict__ s_up, const float* __restrict__ v_up,
    unsigned char* __restrict__ edown) {
  __shared__ unsigned short sH[64 * 72];     // h1 then h2 (wave-private rows)
  __shared__ unsigned short sMix[64 * 200];  // mix; then fp8 staging (stride 232B)
  __shared__ float4 sY[64];

  int t = threadIdx.x;
  int pbase = blockIdx.x * 64;
  int lane = t & 63;
  int wv = t >> 6;
  int rl = lane & 15;
  int kgrp = lane >> 4;
  int arow = 16 * wv + rl;        // A-frag row for this lane
  int crow = 16 * wv + kgrp * 4;  // C rows base (+rr)

  if (t < 64) {
    int2 es = sorted[pbase + t];
    float vx = vectors[(size_t)es.x * 3 + 0];
    float vy = vectors[(size_t)es.x * 3 + 1];
    float vz = vectors[(size_t)es.x * 3 + 2];
    float nrm = sqrtf(vx * vx + vy * vy + vz * vz) + 1e-12f;
    float ysc = Y1C / nrm;
    sY[t] = make_float4(vx * ysc, vy * ysc, vz * ysc, __int_as_float(es.y));
  }

  union S8 { short8 v; unsigned u[4]; };

  // ---- layer 1 ----
  S8 a1;
  a1.u[0] = a1.u[1] = a1.u[2] = a1.u[3] = 0u;
  if (kgrp == 0) {
    int eid = sorted[pbase + arow].x;
    float4 ra = *(const float4*)(rbf + (size_t)eid * 8);
    float4 rb = *(const float4*)(rbf + (size_t)eid * 8 + 4);
    a1.u[0] = packbf(ra.x, ra.y);
    a1.u[1] = packbf(ra.z, ra.w);
    a1.u[2] = packbf(rb.x, rb.y);
    a1.u[3] = packbf(rb.z, rb.w);
  }
#pragma unroll
  for (int ct = 0; ct < 4; ct++) {
    short8 b = *(const short8*)&W1p[(ct * 16 + rl) * 32 + kgrp * 8];
    f32x4 acc = {0.f, 0.f, 0.f, 0.f};
    acc = __builtin_amdgcn_mfma_f32_16x16x32_bf16(a1.v, b, acc, 0, 0, 0);
#pragma unroll
    for (int rr = 0; rr < 4; rr++)
      sH[(crow + rr) * 72 + ct * 16 + rl] = f2bf(silu(acc[rr]));
  }

  // ---- layer 2 (reads own rows, writes own rows; reads precede writes) ----
  {
    short8 a20 = *(const short8*)&sH[arow * 72 + kgrp * 8];
    short8 a21 = *(const short8*)&sH[arow * 72 + 32 + kgrp * 8];
#pragma unroll
    for (int ct = 0; ct < 4; ct++) {
      const unsigned short* wb = &W2p[(ct * 16 + rl) * 64];
      short8 b0 = *(const short8*)&wb[kgrp * 8];
      short8 b1 = *(const short8*)&wb[32 + kgrp * 8];
      f32x4 acc = {0.f, 0.f, 0.f, 0.f};
      acc = __builtin_amdgcn_mfma_f32_16x16x32_bf16(a20, b0, acc, 0, 0, 0);
      acc = __builtin_amdgcn_mfma_f32_16x16x32_bf16(a21, b1, acc, 0, 0, 0);
#pragma unroll
      for (int rr = 0; rr < 4; rr++)
        sH[(crow + rr) * 72 + ct * 16 + rl] = f2bf(silu(acc[rr]));
    }
  }

  // ---- layer 3: mix -> sMix ----
  {
    short8 a30 = *(const short8*)&sH[arow * 72 + kgrp * 8];
    short8 a31 = *(const short8*)&sH[arow * 72 + 32 + kgrp * 8];
#pragma unroll
    for (int nt = 0; nt < 12; nt++) {
      int cc = nt * 16 + rl;
      const unsigned short* wb = &W3b[cc * 64];
      short8 b0 = *(const short8*)&wb[kgrp * 8];
      short8 b1 = *(const short8*)&wb[32 + kgrp * 8];
      f32x4 acc = {0.f, 0.f, 0.f, 0.f};
      acc = __builtin_amdgcn_mfma_f32_16x16x32_bf16(a30, b0, acc, 0, 0, 0);
      acc = __builtin_amdgcn_mfma_f32_16x16x32_bf16(a31, b1, acc, 0, 0, 0);
#pragma unroll
      for (int rr = 0; rr < 4; rr++)
        sMix[(crow + rr) * 200 + cc] = f2bf(acc[rr]);
    }
  }
  __syncthreads();  // BARRIER 1: sY visible to all waves (sMix is own-rows)

  // ---- ph3: build down-proj A-fragments in registers ----
  // msg_s ch k: [0,64)=se[k]*mix[k]; [64,96)=dot(ve[c],y)*mix[64+c] (1/sqrt3 in W3b)
  // msg_v ch c, comp i: [0,32)=ve3[c][i]*mixv[c]; [32,96)=se[c-32]*y_i*mixv[c]
  float4 yv = sY[arow];
  int snd = __float_as_int(yv.w);
  const float* se = s_up + (size_t)snd * 64;
  const float* ve = v_up + (size_t)snd * 96;
  float se1[8], se2[8], vvv[24];
  *(float4*)&se1[0] = *(const float4*)(se + kgrp * 8);
  *(float4*)&se1[4] = *(const float4*)(se + kgrp * 8 + 4);
  *(float4*)&se2[0] = *(const float4*)(se + 32 + kgrp * 8);
  *(float4*)&se2[4] = *(const float4*)(se + 32 + kgrp * 8 + 4);
#pragma unroll
  for (int j = 0; j < 6; j++)
    *(float4*)&vvv[4 * j] = *(const float4*)(ve + 24 * kgrp + 4 * j);

  const unsigned short* mrow = &sMix[arow * 200];
  S8 as0, as1, as2, mvp1, mvp2, mvp3;
  {
    short8 m = *(const short8*)&mrow[kgrp * 8];
#pragma unroll
    for (int q = 0; q < 4; q++)
      as0.u[q] = packbf(se1[2 * q] * bf2f((unsigned short)m[2 * q]),
                        se1[2 * q + 1] * bf2f((unsigned short)m[2 * q + 1]));
  }
  {
    short8 m = *(const short8*)&mrow[32 + kgrp * 8];
#pragma unroll
    for (int q = 0; q < 4; q++)
      as1.u[q] = packbf(se2[2 * q] * bf2f((unsigned short)m[2 * q]),
                        se2[2 * q + 1] * bf2f((unsigned short)m[2 * q + 1]));
  }
  {
    short8 m = *(const short8*)&mrow[64 + kgrp * 8];
#pragma unroll
    for (int q = 0; q < 4; q++) {
      float d0 = vvv[6 * q] * yv.x + vvv[6 * q + 1] * yv.y + vvv[6 * q + 2] * yv.z;
      float d1 = vvv[6 * q + 3] * yv.x + vvv[6 * q + 4] * yv.y + vvv[6 * q + 5] * yv.z;
      as2.u[q] = packbf(d0 * bf2f((unsigned short)m[2 * q]),
                        d1 * bf2f((unsigned short)m[2 * q + 1]));
    }
  }
  mvp1.v = *(const short8*)&mrow[96 + kgrp * 8];
  mvp2.v = *(const short8*)&mrow[128 + kgrp * 8];
  mvp3.v = *(const short8*)&mrow[160 + kgrp * 8];
  __syncthreads();  // BARRIER 2: all sMix reads done before fp8 staging aliases it

  // ---- ph4: down-proj MFMA -> fp8 -> LDS stage (stride 232) ----
  unsigned char* edL = (unsigned char*)sMix;
#pragma unroll
  for (int ot = 0; ot < 8; ot++) {
    int col = ot * 16 + rl;
    const unsigned short* wb = &Wdsb[col * 96];
    short8 b0 = *(const short8*)&wb[kgrp * 8];
    short8 b1 = *(const short8*)&wb[32 + kgrp * 8];
    short8 b2 = *(const short8*)&wb[64 + kgrp * 8];
    f32x4 acc = {0.f, 0.f, 0.f, 0.f};
    acc = __builtin_amdgcn_mfma_f32_16x16x32_bf16(as0.v, b0, acc, 0, 0, 0);
    acc = __builtin_amdgcn_mfma_f32_16x16x32_bf16(as1.v, b1, acc, 0, 0, 0);
    acc = __builtin_amdgcn_mfma_f32_16x16x32_bf16(as2.v, b2, acc, 0, 0, 0);
#pragma unroll
    for (int rr = 0; rr < 4; rr++)
      edL[(crow + rr) * 232 + col] = f2fp8(acc[rr]);
  }
  float yarr[3] = {yv.x, yv.y, yv.z};
#pragma unroll
  for (int i = 0; i < 3; i++) {
    S8 av0, av1, av2;
#pragma unroll
    for (int q = 0; q < 4; q++) {
      av0.u[q] = packbf(
          vvv[3 * (2 * q) + i] * bf2f((unsigned short)mvp1.v[2 * q]),
          vvv[3 * (2 * q + 1) + i] * bf2f((unsigned short)mvp1.v[2 * q + 1]));
      av1.u[q] = packbf(
          se1[2 * q] * yarr[i] * bf2f((unsigned short)mvp2.v[2 * q]),
          se1[2 * q + 1] * yarr[i] * bf2f((unsigned short)mvp2.v[2 * q + 1]));
      av2.u[q] = packbf(
          se2[2 * q] * yarr[i] * bf2f((unsigned short)mvp3.v[2 * q]),
          se2[2 * q + 1] * yarr[i] * bf2f((unsigned short)mvp3.v[2 * q + 1]));
    }
#pragma unroll
    for (int ot = 0; ot < 2; ot++) {
      int o = ot * 16 + rl;
      const unsigned short* wb = &Wdvb[o * 96];
      short8 b0 = *(const short8*)&wb[kgrp * 8];
      short8 b1 = *(const short8*)&wb[32 + kgrp * 8];
      short8 b2 = *(const short8*)&wb[64 + kgrp * 8];
      f32x4 acc = {0.f, 0.f, 0.f, 0.f};
      acc = __builtin_amdgcn_mfma_f32_16x16x32_bf16(av0.v, b0, acc, 0, 0, 0);
      acc = __builtin_amdgcn_mfma_f32_16x16x32_bf16(av1.v, b1, acc, 0, 0, 0);
      acc = __builtin_amdgcn_mfma_f32_16x16x32_bf16(av2.v, b2, acc, 0, 0, 0);
#pragma unroll
      for (int rr = 0; rr < 4; rr++)
        edL[(crow + rr) * 232 + 128 + o * 3 + i] = f2fp8(acc[rr]);
    }
  }
  __syncthreads();  // BARRIER 3: staging complete

  // coalesced copy-out: 224B/row, 64 rows
  {
    int row = t >> 2, q = t & 3;
    const unsigned* src = (const unsigned*)(edL + row * 232 + q * 56);
    unsigned* dst = (unsigned*)(edown + (size_t)(pbase + row) * 224 + q * 56);
#pragma unroll
    for (int j = 0; j < 14; j++) dst[j] = src[j];
  }
}

// ---------------- gather: streaming segmented sum + skip + gate ----------------
__global__ __launch_bounds__(256) void gather_out3(
    const float* __restrict__ nf, const int* __restrict__ species,
    const int* __restrict__ prefix, const unsigned* __restrict__ edw,
    const float* __restrict__ Wss, const float* __restrict__ Wsv,
    float* __restrict__ out) {
  int n = blockIdx.x;
  int t = threadIdx.x;
  __shared__ float sNF[160];
  __shared__ float4 sPart[4][56];
  __shared__ float sEd[224];
  __shared__ float sF[224];
  if (t < 160) sNF[t] = nf[(size_t)n * 160 + t];
  int beg = prefix[n], end = prefix[n + 1];
  if (t < 224) {
    int u = t % 56, rg = t / 56;
    float a0 = 0.f, a1 = 0.f, a2 = 0.f, a3 = 0.f;
    for (int s = beg + rg; s < end; s += 4) {
      unsigned v = edw[(size_t)s * 56 + u];
      a0 += fp82f(v & 0xFF);
      a1 += fp82f((v >> 8) & 0xFF);
      a2 += fp82f((v >> 16) & 0xFF);
      a3 += fp82f(v >> 24);
    }
    sPart[rg][u] = make_float4(a0, a1, a2, a3);
  }
  __syncthreads();
  if (t < 56) {
    float4 a = sPart[0][t], b = sPart[1][t], c = sPart[2][t], d = sPart[3][t];
    sEd[4 * t + 0] = a.x + b.x + c.x + d.x;
    sEd[4 * t + 1] = a.y + b.y + c.y + d.y;
    sEd[4 * t + 2] = a.z + b.z + c.z + d.z;
    sEd[4 * t + 3] = a.w + b.w + c.w + d.w;
  }
  __syncthreads();
  int spec = species[n];
  if (t < 128) {
    const float* wsk = Wss + (size_t)spec * 64 * 128;
    float b = 0.f;
#pragma unroll
    for (int k = 0; k < 64; k++) b += sNF[k] * wsk[k * 128 + t];
    sF[t] = sEd[t] + b * SC_SKIP_S;
  } else if (t < 224) {
    int j = t - 128;
    int c = j / 3, i = j - 3 * c;
    const float* wsk = Wsv + (size_t)spec * 32 * 32;
    float b = 0.f;
#pragma unroll
    for (int k = 0; k < 32; k++) b += sNF[64 + k * 3 + i] * wsk[k * 32 + c];
    sF[t] = sEd[t] + b * SC_SKIP_V;
  }
  __syncthreads();
  if (t < 96) {
    out[(size_t)n * 192 + t] = silu(sF[t]);
  } else if (t < 192) {
    int j = t - 96;
    int c = j / 3;
    out[(size_t)n * 192 + t] = sF[128 + j] * silu(sF[96 + c]);
  }
}

extern "C" void kernel_launch(void* const* d_in, const int* in_sizes, int n_in,
                              void* d_out, int out_size, void* d_ws, size_t ws_size,
                              hipStream_t stream) {
  const float* nf = (const float*)d_in[0];
  const float* vectors = (const float*)d_in[1];
  const float* rbf = (const float*)d_in[2];
  const int* species = (const int*)d_in[3];
  const int* senders = (const int*)d_in[4];
  const int* receivers = (const int*)d_in[5];
  const float* Wus = (const float*)d_in[6];
  const float* Wuv = (const float*)d_in[7];
  const float* W1 = (const float*)d_in[8];
  const float* W2 = (const float*)d_in[9];
  const float* W3 = (const float*)d_in[10];
  const float* Wds = (const float*)d_in[11];
  const float* Wdv = (const float*)d_in[12];
  const float* Wss = (const float*)d_in[13];
  const float* Wsv = (const float*)d_in[14];

  float* ws = (float*)d_ws;
  const unsigned short* W1p = (const unsigned short*)(ws + W_W1P);
  const unsigned short* W2p = (const unsigned short*)(ws + W_W2P);
  const unsigned short* W3b = (const unsigned short*)(ws + W_W3B);
  const unsigned short* Wdsb = (const unsigned short*)(ws + W_WDS);
  const unsigned short* Wdvb = (const unsigned short*)(ws + W_WDV);
  float* s_up = ws + W_SUP;
  float* v_up = ws + W_VUP;
  int* deg = (int*)(ws + W_DEG);
  int* prefix = (int*)(ws + W_PRE);
  int* cursor = (int*)(ws + W_CUR);
  int2* sorted = (int2*)(ws + W_SRT);
  unsigned char* edown = (unsigned char*)(ws + W_EDN);
  float* out = (float*)d_out;

  transpose_weights<<<16, 256, 0, stream>>>(W1, W2, W3, Wds, Wdv, ws);
  up_kernel<<<NN, 256, 0, stream>>>(nf, Wus, Wuv, s_up, v_up);

  hipMemsetAsync(deg, 0, (size_t)NN * sizeof(int), stream);
  count_deg<<<(EE + 255) / 256, 256, 0, stream>>>(receivers, deg);
  scan_kernel<<<1, 1024, 0, stream>>>(deg, prefix);
  copy_cursor<<<(NN + 255) / 256, 256, 0, stream>>>(prefix, cursor);
  scatter_kernel<<<(EE + 255) / 256, 256, 0, stream>>>(senders, receivers,
                                                       cursor, sorted);
  edge_down2<<<EE / 64, 256, 0, stream>>>(rbf, vectors, sorted, W1p, W2p, W3b,
                                          Wdsb, Wdvb, s_up, v_up, edown);
  gather_out3<<<NN, 256, 0, stream>>>(nf, species, prefix, (const unsigned*)edown,
                                      Wss, Wsv, out);
}

// Round 8
// 355.894 us; speedup vs baseline: 23.3780x; 1.0538x over previous
//
#include <hip/hip_runtime.h>
#include <hip/hip_bf16.h>
#include <hip/hip_fp16.h>
#include <hip/hip_fp8.h>

#define NN 25000
#define EE 400000

#define SC_UP_S 0.125f
#define SC_UP_V 0.17677669529663689f
#define Y1C 0.48860251190291992f
#define SC_MLP1 0.35355339059327373f
#define SC_MLP2 0.125f
#define SC3 0.0013020833333333333f      // (1/8)*(1/96) folded into W3
#define INV_SQRT3 0.57735026918962584f  // folded into W3 cols 64..96
#define SC_DOWN 0.025515518153991442f   // (1/4)*(1/sqrt(96)) folded into Wd
#define SC_SKIP_S 0.125f
#define SC_SKIP_V 0.17677669529663689f

typedef __attribute__((ext_vector_type(8))) short short8;
typedef __attribute__((ext_vector_type(4))) float f32x4;

__device__ __forceinline__ float silu(float x) {
  return __fdividef(x, 1.f + __expf(-x));
}
__device__ __forceinline__ unsigned short f2bf(float f) {
  unsigned u = __float_as_uint(f);
  unsigned r = u + 0x7FFF + ((u >> 16) & 1);
  return (unsigned short)(r >> 16);
}
__device__ __forceinline__ float bf2f(unsigned short s) {
  return __uint_as_float(((unsigned)s) << 16);
}
__device__ __forceinline__ float bfe(short8 v, int idx) {  // idx compile-time
  return __uint_as_float(((unsigned)(unsigned short)v[idx]) << 16);
}
__device__ __forceinline__ unsigned packbf(float lo, float hi) {
  return ((unsigned)f2bf(hi) << 16) | (unsigned)f2bf(lo);
}
__device__ __forceinline__ unsigned char f2fp8(float x) {
  __hip_fp8_e4m3 v(x);
  return (unsigned char)v.__x;
}
__device__ __forceinline__ float fp82f(unsigned b) {
  __hip_fp8_e4m3 t;
  t.__x = (__hip_fp8_storage_t)b;
  return (float)t;
}

// ---------------- workspace layout (4-byte word offsets) ----------------
#define W_W1P 0                        // 64x32 bf16 (K zero-padded 8->32)
#define W_W2P 1024                     // 64x64 bf16 [col][k]
#define W_W3B 3072                     // 192x64 bf16 [col][k]
#define W_WDS 9216                     // 128x96 bf16 [col][k]
#define W_WDV 15360                    // 32x96 bf16 [col][k]
#define W_SUPB 16896                   // NN*64 bf16 = NN*32 words
#define W_VUPB (W_SUPB + NN * 32)      // NN*96 bf16 = NN*48 words
#define W_DEG (W_VUPB + NN * 48)
#define W_PRE (W_DEG + NN)
#define W_CUR (W_PRE + NN + 8)
#define W_SRT (W_CUR + NN)             // int2 per slot (even offset)
#define W_EDN (W_SRT + EE * 2)         // fp8: EE*224 bytes = EE*56 words
#define W_END (W_EDN + EE * 56)

// ---------------- setup: weight transforms ----------------
__global__ __launch_bounds__(256) void transpose_weights(
    const float* __restrict__ W1, const float* __restrict__ W2,
    const float* __restrict__ W3, const float* __restrict__ Wds,
    const float* __restrict__ Wdv, float* __restrict__ ws) {
  int t = blockIdx.x * 256 + threadIdx.x;
  int stride = gridDim.x * 256;
  unsigned short* W1p = (unsigned short*)(ws + W_W1P);
  unsigned short* W2p = (unsigned short*)(ws + W_W2P);
  unsigned short* W3b = (unsigned short*)(ws + W_W3B);
  unsigned short* Wdsb = (unsigned short*)(ws + W_WDS);
  unsigned short* Wdvb = (unsigned short*)(ws + W_WDV);
  for (int i = t; i < 2048; i += stride) {  // W1p[c*32+k], k<8 real
    int c = i >> 5, k = i & 31;
    W1p[i] = (k < 8) ? f2bf(W1[k * 64 + c] * SC_MLP1) : (unsigned short)0;
  }
  for (int i = t; i < 4096; i += stride) {  // W2p[c*64+k]
    int c = i >> 6, k = i & 63;
    W2p[i] = f2bf(W2[k * 64 + c] * SC_MLP2);
  }
  for (int i = t; i < 12288; i += stride) { // W3b[c*64+k]; 1/sqrt3 fold c in [64,96)
    int c = i >> 6, k = i & 63;
    float sc = (c >= 64 && c < 96) ? (SC3 * INV_SQRT3) : SC3;
    W3b[i] = f2bf(W3[k * 192 + c] * sc);
  }
  for (int i = t; i < 12288; i += stride) { // Wdsb[o*96+k]
    int o = i / 96, k = i - 96 * o;
    Wdsb[i] = f2bf(Wds[k * 128 + o] * SC_DOWN);
  }
  for (int i = t; i < 3072; i += stride) {  // Wdvb[o*96+k]
    int o = i / 96, k = i - 96 * o;
    Wdvb[i] = f2bf(Wdv[k * 32 + o] * SC_DOWN);
  }
}

// ---------------- per-node up-projection (fp32 math, bf16 out) ----------------
__global__ __launch_bounds__(256) void up_kernel(
    const float* __restrict__ nf, const float* __restrict__ Wus,
    const float* __restrict__ Wuv, unsigned short* __restrict__ s_upb,
    unsigned short* __restrict__ v_upb) {
  int n = blockIdx.x;
  int t = threadIdx.x;
  __shared__ float sv[160];
  if (t < 160) sv[t] = nf[n * 160 + t];
  __syncthreads();
  if (t < 64) {
    float a = 0.f;
#pragma unroll
    for (int k = 0; k < 64; k++) a += sv[k] * Wus[k * 64 + t];
    s_upb[n * 64 + t] = f2bf(a * SC_UP_S);
  } else if (t < 160) {
    int j = t - 64;
    int c = j / 3, i = j - 3 * c;
    float a = 0.f;
#pragma unroll
    for (int k = 0; k < 32; k++) a += sv[64 + k * 3 + i] * Wuv[k * 32 + c];
    v_upb[n * 96 + j] = f2bf(a * SC_UP_V);
  }
}

// ---------------- counting sort by receiver ----------------
__global__ __launch_bounds__(256) void count_deg(
    const int* __restrict__ receivers, int* __restrict__ deg) {
  int e = blockIdx.x * 256 + threadIdx.x;
  if (e < EE) atomicAdd(&deg[receivers[e]], 1);
}

__global__ __launch_bounds__(1024) void scan_kernel(
    const int* __restrict__ deg, int* __restrict__ prefix,
    int* __restrict__ cursor) {
  __shared__ int waveSums[16];
  __shared__ int sCarry;
  int t = threadIdx.x;
  int lane = t & 63, wv = t >> 6;
  if (t == 0) sCarry = 0;
  __syncthreads();
  for (int base = 0; base < NN; base += 1024) {
    int i = base + t;
    int x = (i < NN) ? deg[i] : 0;
    int v = x;
#pragma unroll
    for (int d = 1; d < 64; d <<= 1) {
      int u = __shfl_up(v, d, 64);
      if (lane >= d) v += u;
    }
    if (lane == 63) waveSums[wv] = v;
    __syncthreads();
    if (wv == 0 && lane < 16) {
      int s = waveSums[lane];
#pragma unroll
      for (int d = 1; d < 16; d <<= 1) {
        int u = __shfl_up(s, d, 64);
        if (lane >= d) s += u;
      }
      waveSums[lane] = s;
    }
    __syncthreads();
    int waveOff = (wv == 0) ? 0 : waveSums[wv - 1];
    int incl = v + waveOff + sCarry;
    if (i < NN) {
      prefix[i] = incl - x;
      cursor[i] = incl - x;
    }
    __syncthreads();
    if (t == 1023) sCarry = incl;
    __syncthreads();
  }
  if (t == 0) prefix[NN] = sCarry;
}

__global__ __launch_bounds__(256) void scatter_kernel(
    const int* __restrict__ senders, const int* __restrict__ receivers,
    int* __restrict__ cursor, int2* __restrict__ sorted) {
  int e = blockIdx.x * 256 + threadIdx.x;
  if (e < EE) {
    int r = receivers[e];
    int pos = atomicAdd(&cursor[r], 1);
    sorted[pos] = make_int2(e, senders[e]);
  }
}

// ---------------- fused edge pipeline, all-MFMA, prefetched gathers ----------------
// Block = 256 thr / 4 waves / 64 edges. Wave w owns rows [16w,16w+16) of every
// LDS buffer. Sender features + rbf prefetched at entry (latency hidden under
// the 3-layer MLP). y computed per-lane. 2 barriers total.
__global__ __launch_bounds__(256, 4) void edge_down3(
    const float* __restrict__ rbf, const float* __restrict__ vectors,
    const int2* __restrict__ sorted,
    const unsigned short* __restrict__ W1p,
    const unsigned short* __restrict__ W2p,
    const unsigned short* __restrict__ W3b,
    const unsigned short* __restrict__ Wdsb,
    const unsigned short* __restrict__ Wdvb,
    const unsigned short* __restrict__ s_upb,
    const unsigned short* __restrict__ v_upb,
    unsigned char* __restrict__ edown) {
  __shared__ unsigned short sH[64 * 72];     // h1 then h2 (wave-private rows)
  __shared__ unsigned short sMix[64 * 200];  // mix; then fp8 staging (stride 232B)

  int t = threadIdx.x;
  int pbase = blockIdx.x * 64;
  int lane = t & 63;
  int wv = t >> 6;
  int rl = lane & 15;
  int kgrp = lane >> 4;
  int arow = 16 * wv + rl;        // this lane's edge row (A-frag row)
  int crow = 16 * wv + kgrp * 4;  // C rows base (+rr)

  union S8 { short8 v; unsigned u[4]; };

  // ---- entry: prefetch everything this lane will need in ph3/ph4 ----
  int2 es = sorted[pbase + arow];
  int eid = es.x, snd = es.y;
  const unsigned short* seb = s_upb + (size_t)snd * 64;
  const unsigned short* veb = v_upb + (size_t)snd * 96;
  short8 se0 = *(const short8*)&seb[kgrp * 8];        // s_e[8k..8k+8)
  short8 se1 = *(const short8*)&seb[32 + kgrp * 8];   // s_e[32+8k..)
  short8 ve0 = *(const short8*)&veb[24 * kgrp];       // v_e flat [24k..24k+24)
  short8 ve1 = *(const short8*)&veb[24 * kgrp + 8];
  short8 ve2 = *(const short8*)&veb[24 * kgrp + 16];
  float vx = vectors[(size_t)eid * 3 + 0];
  float vy = vectors[(size_t)eid * 3 + 1];
  float vz = vectors[(size_t)eid * 3 + 2];
  float nrm = sqrtf(vx * vx + vy * vy + vz * vz) + 1e-12f;
  float ysc = Y1C / nrm;
  float y0 = vx * ysc, y1 = vy * ysc, y2 = vz * ysc;

  // ---- layer 1: h1 = silu(rbf @ W1) ----
  S8 a1;
  a1.u[0] = a1.u[1] = a1.u[2] = a1.u[3] = 0u;
  if (kgrp == 0) {
    float4 ra = *(const float4*)(rbf + (size_t)eid * 8);
    float4 rb = *(const float4*)(rbf + (size_t)eid * 8 + 4);
    a1.u[0] = packbf(ra.x, ra.y);
    a1.u[1] = packbf(ra.z, ra.w);
    a1.u[2] = packbf(rb.x, rb.y);
    a1.u[3] = packbf(rb.z, rb.w);
  }
#pragma unroll
  for (int ct = 0; ct < 4; ct++) {
    short8 b = *(const short8*)&W1p[(ct * 16 + rl) * 32 + kgrp * 8];
    f32x4 acc = {0.f, 0.f, 0.f, 0.f};
    acc = __builtin_amdgcn_mfma_f32_16x16x32_bf16(a1.v, b, acc, 0, 0, 0);
#pragma unroll
    for (int rr = 0; rr < 4; rr++)
      sH[(crow + rr) * 72 + ct * 16 + rl] = f2bf(silu(acc[rr]));
  }

  // ---- layer 2 ----
  {
    short8 a20 = *(const short8*)&sH[arow * 72 + kgrp * 8];
    short8 a21 = *(const short8*)&sH[arow * 72 + 32 + kgrp * 8];
#pragma unroll
    for (int ct = 0; ct < 4; ct++) {
      const unsigned short* wb = &W2p[(ct * 16 + rl) * 64];
      short8 b0 = *(const short8*)&wb[kgrp * 8];
      short8 b1 = *(const short8*)&wb[32 + kgrp * 8];
      f32x4 acc = {0.f, 0.f, 0.f, 0.f};
      acc = __builtin_amdgcn_mfma_f32_16x16x32_bf16(a20, b0, acc, 0, 0, 0);
      acc = __builtin_amdgcn_mfma_f32_16x16x32_bf16(a21, b1, acc, 0, 0, 0);
#pragma unroll
      for (int rr = 0; rr < 4; rr++)
        sH[(crow + rr) * 72 + ct * 16 + rl] = f2bf(silu(acc[rr]));
    }
  }

  // ---- layer 3: mix -> sMix (wave-private rows) ----
  {
    short8 a30 = *(const short8*)&sH[arow * 72 + kgrp * 8];
    short8 a31 = *(const short8*)&sH[arow * 72 + 32 + kgrp * 8];
#pragma unroll
    for (int nt = 0; nt < 12; nt++) {
      int cc = nt * 16 + rl;
      const unsigned short* wb = &W3b[cc * 64];
      short8 b0 = *(const short8*)&wb[kgrp * 8];
      short8 b1 = *(const short8*)&wb[32 + kgrp * 8];
      f32x4 acc = {0.f, 0.f, 0.f, 0.f};
      acc = __builtin_amdgcn_mfma_f32_16x16x32_bf16(a30, b0, acc, 0, 0, 0);
      acc = __builtin_amdgcn_mfma_f32_16x16x32_bf16(a31, b1, acc, 0, 0, 0);
#pragma unroll
      for (int rr = 0; rr < 4; rr++)
        sMix[(crow + rr) * 200 + cc] = f2bf(acc[rr]);
    }
  }

  // ---- ph3: build down-proj A-fragments in registers (prefetched se/ve) ----
  // msg_s ch k: [0,64)=se[k]*mix[k]; [64,96)=dot(ve[c],y)*mix[64+c] (1/sqrt3 in W3b)
  // msg_v ch c, comp i: [0,32)=ve3[c][i]*mixv[c]; [32,96)=se[c-32]*y_i*mixv[c]
  const unsigned short* mrow = &sMix[arow * 200];
  S8 as0, as1, as2, mvp1, mvp2, mvp3;
  {
    short8 m = *(const short8*)&mrow[kgrp * 8];
#pragma unroll
    for (int q = 0; q < 4; q++)
      as0.u[q] = packbf(bfe(se0, 2 * q) * bfe(m, 2 * q),
                        bfe(se0, 2 * q + 1) * bfe(m, 2 * q + 1));
  }
  {
    short8 m = *(const short8*)&mrow[32 + kgrp * 8];
#pragma unroll
    for (int q = 0; q < 4; q++)
      as1.u[q] = packbf(bfe(se1, 2 * q) * bfe(m, 2 * q),
                        bfe(se1, 2 * q + 1) * bfe(m, 2 * q + 1));
  }
  {
    short8 m = *(const short8*)&mrow[64 + kgrp * 8];
#pragma unroll
    for (int q = 0; q < 4; q++) {
      // tp_s channels 8*kgrp + 2q, 2q+1: dot(v_e[c], y)
      float d0 = bfe(ve0, (6 * q) % 8 == 6 * q ? 6 * q : 6 * q) * 0.f;  // (placeholder, replaced below)
      (void)d0;
      float e0, e1, e2, f0, f1, f2;
      // element j of flat ve = component (j%3) of channel kgrp*8 + j/3
      // channels 2q -> flat 6q..6q+2 ; 2q+1 -> 6q+3..6q+5
      if (6 * q < 8) e0 = bfe(ve0, 6 * q); else if (6 * q < 16) e0 = bfe(ve1, 6 * q - 8); else e0 = bfe(ve2, 6 * q - 16);
      if (6 * q + 1 < 8) e1 = bfe(ve0, 6 * q + 1); else if (6 * q + 1 < 16) e1 = bfe(ve1, 6 * q - 7); else e1 = bfe(ve2, 6 * q - 15);
      if (6 * q + 2 < 8) e2 = bfe(ve0, 6 * q + 2); else if (6 * q + 2 < 16) e2 = bfe(ve1, 6 * q - 6); else e2 = bfe(ve2, 6 * q - 14);
      if (6 * q + 3 < 8) f0 = bfe(ve0, 6 * q + 3); else if (6 * q + 3 < 16) f0 = bfe(ve1, 6 * q - 5); else f0 = bfe(ve2, 6 * q - 13);
      if (6 * q + 4 < 8) f1 = bfe(ve0, 6 * q + 4); else if (6 * q + 4 < 16) f1 = bfe(ve1, 6 * q - 4); else f1 = bfe(ve2, 6 * q - 12);
      if (6 * q + 5 < 8) f2 = bfe(ve0, 6 * q + 5); else if (6 * q + 5 < 16) f2 = bfe(ve1, 6 * q - 3); else f2 = bfe(ve2, 6 * q - 11);
      float da = e0 * y0 + e1 * y1 + e2 * y2;
      float db = f0 * y0 + f1 * y1 + f2 * y2;
      as2.u[q] = packbf(da * bfe(m, 2 * q), db * bfe(m, 2 * q + 1));
    }
  }
  mvp1.v = *(const short8*)&mrow[96 + kgrp * 8];
  mvp2.v = *(const short8*)&mrow[128 + kgrp * 8];
  mvp3.v = *(const short8*)&mrow[160 + kgrp * 8];
  __syncthreads();  // BARRIER 1: sMix reads done before fp8 staging aliases it

  // ---- ph4: down-proj MFMA -> fp8 -> LDS stage (stride 232) ----
  unsigned char* edL = (unsigned char*)sMix;
#pragma unroll
  for (int ot = 0; ot < 8; ot++) {
    int col = ot * 16 + rl;
    const unsigned short* wb = &Wdsb[col * 96];
    short8 b0 = *(const short8*)&wb[kgrp * 8];
    short8 b1 = *(const short8*)&wb[32 + kgrp * 8];
    short8 b2 = *(const short8*)&wb[64 + kgrp * 8];
    f32x4 acc = {0.f, 0.f, 0.f, 0.f};
    acc = __builtin_amdgcn_mfma_f32_16x16x32_bf16(as0.v, b0, acc, 0, 0, 0);
    acc = __builtin_amdgcn_mfma_f32_16x16x32_bf16(as1.v, b1, acc, 0, 0, 0);
    acc = __builtin_amdgcn_mfma_f32_16x16x32_bf16(as2.v, b2, acc, 0, 0, 0);
#pragma unroll
    for (int rr = 0; rr < 4; rr++)
      edL[(crow + rr) * 232 + col] = f2fp8(acc[rr]);
  }
  float yarr[3] = {y0, y1, y2};
#pragma unroll
  for (int i = 0; i < 3; i++) {
    S8 av0, av1, av2;
#pragma unroll
    for (int q = 0; q < 4; q++) {
      // v_e comp i of channels kgrp*8 + 2q, 2q+1 -> flat 3*(2q)+i, 3*(2q+1)+i
      float g0, g1;
      {
        const int j0 = 0;  // dummy to keep structure
        (void)j0;
      }
      int ja = 6 * q + i, jb = 6 * q + 3 + i;  // compile-time in unrolled loop
      if (ja < 8) g0 = bfe(ve0, ja); else if (ja < 16) g0 = bfe(ve1, ja - 8); else g0 = bfe(ve2, ja - 16);
      if (jb < 8) g1 = bfe(ve0, jb); else if (jb < 16) g1 = bfe(ve1, jb - 8); else g1 = bfe(ve2, jb - 16);
      av0.u[q] = packbf(g0 * bfe(mvp1.v, 2 * q), g1 * bfe(mvp1.v, 2 * q + 1));
      av1.u[q] = packbf(bfe(se0, 2 * q) * yarr[i] * bfe(mvp2.v, 2 * q),
                        bfe(se0, 2 * q + 1) * yarr[i] * bfe(mvp2.v, 2 * q + 1));
      av2.u[q] = packbf(bfe(se1, 2 * q) * yarr[i] * bfe(mvp3.v, 2 * q),
                        bfe(se1, 2 * q + 1) * yarr[i] * bfe(mvp3.v, 2 * q + 1));
    }
#pragma unroll
    for (int ot = 0; ot < 2; ot++) {
      int o = ot * 16 + rl;
      const unsigned short* wb = &Wdvb[o * 96];
      short8 b0 = *(const short8*)&wb[kgrp * 8];
      short8 b1 = *(const short8*)&wb[32 + kgrp * 8];
      short8 b2 = *(const short8*)&wb[64 + kgrp * 8];
      f32x4 acc = {0.f, 0.f, 0.f, 0.f};
      acc = __builtin_amdgcn_mfma_f32_16x16x32_bf16(av0.v, b0, acc, 0, 0, 0);
      acc = __builtin_amdgcn_mfma_f32_16x16x32_bf16(av1.v, b1, acc, 0, 0, 0);
      acc = __builtin_amdgcn_mfma_f32_16x16x32_bf16(av2.v, b2, acc, 0, 0, 0);
#pragma unroll
      for (int rr = 0; rr < 4; rr++)
        edL[(crow + rr) * 232 + 128 + o * 3 + i] = f2fp8(acc[rr]);
    }
  }
  __syncthreads();  // BARRIER 2: staging complete

  // coalesced copy-out: 224B/row, 64 rows
  {
    int row = t >> 2, q = t & 3;
    const unsigned* src = (const unsigned*)(edL + row * 232 + q * 56);
    unsigned* dst = (unsigned*)(edown + (size_t)(pbase + row) * 224 + q * 56);
#pragma unroll
    for (int j = 0; j < 14; j++) dst[j] = src[j];
  }
}

// ---------------- gather: streaming segmented sum + skip + gate ----------------
__global__ __launch_bounds__(256) void gather_out3(
    const float* __restrict__ nf, const int* __restrict__ species,
    const int* __restrict__ prefix, const unsigned* __restrict__ edw,
    const float* __restrict__ Wss, const float* __restrict__ Wsv,
    float* __restrict__ out) {
  int n = blockIdx.x;
  int t = threadIdx.x;
  __shared__ float sNF[160];
  __shared__ float4 sPart[4][56];
  __shared__ float sEd[224];
  __shared__ float sF[224];
  if (t < 160) sNF[t] = nf[(size_t)n * 160 + t];
  int beg = prefix[n], end = prefix[n + 1];
  if (t < 224) {
    int u = t % 56, rg = t / 56;
    float a0 = 0.f, a1 = 0.f, a2 = 0.f, a3 = 0.f;
    for (int s = beg + rg; s < end; s += 4) {
      unsigned v = edw[(size_t)s * 56 + u];
      a0 += fp82f(v & 0xFF);
      a1 += fp82f((v >> 8) & 0xFF);
      a2 += fp82f((v >> 16) & 0xFF);
      a3 += fp82f(v >> 24);
    }
    sPart[rg][u] = make_float4(a0, a1, a2, a3);
  }
  __syncthreads();
  if (t < 56) {
    float4 a = sPart[0][t], b = sPart[1][t], c = sPart[2][t], d = sPart[3][t];
    sEd[4 * t + 0] = a.x + b.x + c.x + d.x;
    sEd[4 * t + 1] = a.y + b.y + c.y + d.y;
    sEd[4 * t + 2] = a.z + b.z + c.z + d.z;
    sEd[4 * t + 3] = a.w + b.w + c.w + d.w;
  }
  __syncthreads();
  int spec = species[n];
  if (t < 128) {
    const float* wsk = Wss + (size_t)spec * 64 * 128;
    float b = 0.f;
#pragma unroll
    for (int k = 0; k < 64; k++) b += sNF[k] * wsk[k * 128 + t];
    sF[t] = sEd[t] + b * SC_SKIP_S;
  } else if (t < 224) {
    int j = t - 128;
    int c = j / 3, i = j - 3 * c;
    const float* wsk = Wsv + (size_t)spec * 32 * 32;
    float b = 0.f;
#pragma unroll
    for (int k = 0; k < 32; k++) b += sNF[64 + k * 3 + i] * wsk[k * 32 + c];
    sF[t] = sEd[t] + b * SC_SKIP_V;
  }
  __syncthreads();
  if (t < 96) {
    out[(size_t)n * 192 + t] = silu(sF[t]);
  } else if (t < 192) {
    int j = t - 96;
    int c = j / 3;
    out[(size_t)n * 192 + t] = sF[128 + j] * silu(sF[96 + c]);
  }
}

extern "C" void kernel_launch(void* const* d_in, const int* in_sizes, int n_in,
                              void* d_out, int out_size, void* d_ws, size_t ws_size,
                              hipStream_t stream) {
  const float* nf = (const float*)d_in[0];
  const float* vectors = (const float*)d_in[1];
  const float* rbf = (const float*)d_in[2];
  const int* species = (const int*)d_in[3];
  const int* senders = (const int*)d_in[4];
  const int* receivers = (const int*)d_in[5];
  const float* Wus = (const float*)d_in[6];
  const float* Wuv = (const float*)d_in[7];
  const float* W1 = (const float*)d_in[8];
  const float* W2 = (const float*)d_in[9];
  const float* W3 = (const float*)d_in[10];
  const float* Wds = (const float*)d_in[11];
  const float* Wdv = (const float*)d_in[12];
  const float* Wss = (const float*)d_in[13];
  const float* Wsv = (const float*)d_in[14];

  float* ws = (float*)d_ws;
  const unsigned short* W1p = (const unsigned short*)(ws + W_W1P);
  const unsigned short* W2p = (const unsigned short*)(ws + W_W2P);
  const unsigned short* W3b = (const unsigned short*)(ws + W_W3B);
  const unsigned short* Wdsb = (const unsigned short*)(ws + W_WDS);
  const unsigned short* Wdvb = (const unsigned short*)(ws + W_WDV);
  unsigned short* s_upb = (unsigned short*)(ws + W_SUPB);
  unsigned short* v_upb = (unsigned short*)(ws + W_VUPB);
  int* deg = (int*)(ws + W_DEG);
  int* prefix = (int*)(ws + W_PRE);
  int* cursor = (int*)(ws + W_CUR);
  int2* sorted = (int2*)(ws + W_SRT);
  unsigned char* edown = (unsigned char*)(ws + W_EDN);
  float* out = (float*)d_out;

  transpose_weights<<<16, 256, 0, stream>>>(W1, W2, W3, Wds, Wdv, ws);
  up_kernel<<<NN, 256, 0, stream>>>(nf, Wus, Wuv, s_upb, v_upb);

  hipMemsetAsync(deg, 0, (size_t)NN * sizeof(int), stream);
  count_deg<<<(EE + 255) / 256, 256, 0, stream>>>(receivers, deg);
  scan_kernel<<<1, 1024, 0, stream>>>(deg, prefix, cursor);
  scatter_kernel<<<(EE + 255) / 256, 256, 0, stream>>>(senders, receivers,
                                                       cursor, sorted);
  edge_down3<<<EE / 64, 256, 0, stream>>>(rbf, vectors, sorted, W1p, W2p, W3b,
                                          Wdsb, Wdvb, s_upb, v_upb, edown);
  gather_out3<<<NN, 256, 0, stream>>>(nf, species, prefix, (const unsigned*)edown,
                                      Wss, Wsv, out);
}

// Round 9
// 349.292 us; speedup vs baseline: 23.8199x; 1.0189x over previous
//
#include <hip/hip_runtime.h>
#include <hip/hip_bf16.h>
#include <hip/hip_fp16.h>
#include <hip/hip_fp8.h>

#define NN 25000
#define EE 400000

#define SC_UP_S 0.125f
#define SC_UP_V 0.17677669529663689f
#define Y1C 0.48860251190291992f
#define SC_MLP1 0.35355339059327373f
#define SC_MLP2 0.125f
#define SC3 0.0013020833333333333f      // (1/8)*(1/96) folded into W3
#define INV_SQRT3 0.57735026918962584f  // folded into W3 cols 64..96
#define SC_DOWN 0.025515518153991442f   // (1/4)*(1/sqrt(96)) folded into Wd
#define SC_SKIP_S 0.125f                // folded into Wssb
#define SC_SKIP_V 0.17677669529663689f  // folded into Wsvb

typedef __attribute__((ext_vector_type(8))) short short8;
typedef __attribute__((ext_vector_type(4))) float f32x4;

__device__ __forceinline__ float silu(float x) {
  return __fdividef(x, 1.f + __expf(-x));
}
__device__ __forceinline__ unsigned short f2bf(float f) {
  __hip_bfloat16 h = __float2bfloat16(f);  // HW cvt, RTNE
  return *reinterpret_cast<unsigned short*>(&h);
}
__device__ __forceinline__ float bf2f(unsigned short s) {
  return __uint_as_float(((unsigned)s) << 16);
}
__device__ __forceinline__ float bfe(short8 v, int idx) {  // idx compile-time
  return __uint_as_float(((unsigned)(unsigned short)v[idx]) << 16);
}
__device__ __forceinline__ unsigned packbf(float lo, float hi) {
  return ((unsigned)f2bf(hi) << 16) | (unsigned)f2bf(lo);
}
__device__ __forceinline__ unsigned char f2fp8(float x) {
  __hip_fp8_e4m3 v(x);
  return (unsigned char)v.__x;
}
__device__ __forceinline__ float fp82f(unsigned b) {
  __hip_fp8_e4m3 t;
  t.__x = (__hip_fp8_storage_t)b;
  return (float)t;
}

// ---------------- workspace layout (4-byte word offsets) ----------------
#define W_W1P 0                         // 64x32 bf16 (K zero-padded 8->32)
#define W_W2P 1024                      // 64x64 bf16 [col][k]
#define W_W3B 3072                      // 192x64 bf16 [col][k]
#define W_WDS 9216                      // 128x96 bf16 [col][k]
#define W_WDV 15360                     // 32x96 bf16 [col][k]
#define W_WSS 16896                     // 4x64x128 bf16 (skip_s, scale folded)
#define W_WSV 33280                     // 4x32x32 bf16 (skip_v, scale folded)
#define W_SUPB 35328                    // NN*64 bf16
#define W_VUPB (W_SUPB + NN * 32)       // NN*96 bf16
#define W_DEG (W_VUPB + NN * 48)
#define W_PRE (W_DEG + NN)
#define W_CUR (W_PRE + NN + 8)
#define W_RNK (W_CUR + NN)              // rank[e] = sorted position
#define W_EDN (W_RNK + EE)              // fp8: EE*224 bytes = EE*56 words
#define W_END (W_EDN + EE * 56)         // ~99.6 MB

// ---------------- setup: weight transforms ----------------
__global__ __launch_bounds__(256) void transpose_weights(
    const float* __restrict__ W1, const float* __restrict__ W2,
    const float* __restrict__ W3, const float* __restrict__ Wds,
    const float* __restrict__ Wdv, const float* __restrict__ Wss,
    const float* __restrict__ Wsv, float* __restrict__ ws) {
  int t = blockIdx.x * 256 + threadIdx.x;
  int stride = gridDim.x * 256;
  unsigned short* W1p = (unsigned short*)(ws + W_W1P);
  unsigned short* W2p = (unsigned short*)(ws + W_W2P);
  unsigned short* W3b = (unsigned short*)(ws + W_W3B);
  unsigned short* Wdsb = (unsigned short*)(ws + W_WDS);
  unsigned short* Wdvb = (unsigned short*)(ws + W_WDV);
  unsigned short* Wssb = (unsigned short*)(ws + W_WSS);
  unsigned short* Wsvb = (unsigned short*)(ws + W_WSV);
  for (int i = t; i < 2048; i += stride) {  // W1p[c*32+k], k<8 real
    int c = i >> 5, k = i & 31;
    W1p[i] = (k < 8) ? f2bf(W1[k * 64 + c] * SC_MLP1) : (unsigned short)0;
  }
  for (int i = t; i < 4096; i += stride) {  // W2p[c*64+k]
    int c = i >> 6, k = i & 63;
    W2p[i] = f2bf(W2[k * 64 + c] * SC_MLP2);
  }
  for (int i = t; i < 12288; i += stride) { // W3b[c*64+k]; 1/sqrt3 fold c in [64,96)
    int c = i >> 6, k = i & 63;
    float sc = (c >= 64 && c < 96) ? (SC3 * INV_SQRT3) : SC3;
    W3b[i] = f2bf(W3[k * 192 + c] * sc);
  }
  for (int i = t; i < 12288; i += stride) { // Wdsb[o*96+k]
    int o = i / 96, k = i - 96 * o;
    Wdsb[i] = f2bf(Wds[k * 128 + o] * SC_DOWN);
  }
  for (int i = t; i < 3072; i += stride) {  // Wdvb[o*96+k]
    int o = i / 96, k = i - 96 * o;
    Wdvb[i] = f2bf(Wdv[k * 32 + o] * SC_DOWN);
  }
  for (int i = t; i < 32768; i += stride)   // Wssb: same layout, scale folded
    Wssb[i] = f2bf(Wss[i] * SC_SKIP_S);
  for (int i = t; i < 4096; i += stride)    // Wsvb
    Wsvb[i] = f2bf(Wsv[i] * SC_SKIP_V);
}

// ---------------- per-node up-projection (fp32 math, bf16 out) ----------------
__global__ __launch_bounds__(256) void up_kernel(
    const float* __restrict__ nf, const float* __restrict__ Wus,
    const float* __restrict__ Wuv, unsigned short* __restrict__ s_upb,
    unsigned short* __restrict__ v_upb) {
  int n = blockIdx.x;
  int t = threadIdx.x;
  __shared__ float sv[160];
  if (t < 160) sv[t] = nf[n * 160 + t];
  __syncthreads();
  if (t < 64) {
    float a = 0.f;
#pragma unroll
    for (int k = 0; k < 64; k++) a += sv[k] * Wus[k * 64 + t];
    s_upb[n * 64 + t] = f2bf(a * SC_UP_S);
  } else if (t < 160) {
    int j = t - 64;
    int c = j / 3, i = j - 3 * c;
    float a = 0.f;
#pragma unroll
    for (int k = 0; k < 32; k++) a += sv[64 + k * 3 + i] * Wuv[k * 32 + c];
    v_upb[n * 96 + j] = f2bf(a * SC_UP_V);
  }
}

// ---------------- counting sort (rank only) ----------------
__global__ __launch_bounds__(256) void count_deg(
    const int* __restrict__ receivers, int* __restrict__ deg) {
  int e = blockIdx.x * 256 + threadIdx.x;
  if (e < EE) atomicAdd(&deg[receivers[e]], 1);
}

__global__ __launch_bounds__(1024) void scan_kernel(
    const int* __restrict__ deg, int* __restrict__ prefix,
    int* __restrict__ cursor) {
  __shared__ int waveSums[16];
  __shared__ int sCarry;
  int t = threadIdx.x;
  int lane = t & 63, wv = t >> 6;
  if (t == 0) sCarry = 0;
  __syncthreads();
  for (int base = 0; base < NN; base += 1024) {
    int i = base + t;
    int x = (i < NN) ? deg[i] : 0;
    int v = x;
#pragma unroll
    for (int d = 1; d < 64; d <<= 1) {
      int u = __shfl_up(v, d, 64);
      if (lane >= d) v += u;
    }
    if (lane == 63) waveSums[wv] = v;
    __syncthreads();
    if (wv == 0 && lane < 16) {
      int s = waveSums[lane];
#pragma unroll
      for (int d = 1; d < 16; d <<= 1) {
        int u = __shfl_up(s, d, 64);
        if (lane >= d) s += u;
      }
      waveSums[lane] = s;
    }
    __syncthreads();
    int waveOff = (wv == 0) ? 0 : waveSums[wv - 1];
    int incl = v + waveOff + sCarry;
    if (i < NN) {
      prefix[i] = incl - x;
      cursor[i] = incl - x;
    }
    __syncthreads();
    if (t == 1023) sCarry = incl;
    __syncthreads();
  }
  if (t == 0) prefix[NN] = sCarry;
}

__global__ __launch_bounds__(256) void rank_kernel(
    const int* __restrict__ receivers, int* __restrict__ cursor,
    int* __restrict__ rankArr) {
  int e = blockIdx.x * 256 + threadIdx.x;
  if (e < EE) {
    int r = receivers[e];
    rankArr[e] = atomicAdd(&cursor[r], 1);
  }
}

// ---------------- fused edge pipeline: natural order, scatter-write ----------------
// Block = 256 thr / 4 waves / 64 edges (eid = pbase + row, NO indirection).
// rbf/vectors/senders coalesced; only se/ve gather scattered (prefetched,
// consumed ~2000cy later). Output rows scatter-written to rank[eid]*224.
__global__ __launch_bounds__(256, 4) void edge_down4(
    const float* __restrict__ rbf, const float* __restrict__ vectors,
    const int* __restrict__ senders, const int* __restrict__ rankArr,
    const unsigned short* __restrict__ W1p,
    const unsigned short* __restrict__ W2p,
    const unsigned short* __restrict__ W3b,
    const unsigned short* __restrict__ Wdsb,
    const unsigned short* __restrict__ Wdvb,
    const unsigned short* __restrict__ s_upb,
    const unsigned short* __restrict__ v_upb,
    unsigned char* __restrict__ edown) {
  __shared__ unsigned short sH[64 * 72];     // h1 then h2 (wave-private rows)
  __shared__ unsigned short sMix[64 * 200];  // mix; then fp8 staging (stride 232B)
  __shared__ int sRank[64];

  int t = threadIdx.x;
  int pbase = blockIdx.x * 64;
  int lane = t & 63;
  int wv = t >> 6;
  int rl = lane & 15;
  int kgrp = lane >> 4;
  int arow = 16 * wv + rl;        // this lane's edge row
  int crow = 16 * wv + kgrp * 4;  // C rows base (+rr)

  union S8 { short8 v; unsigned u[4]; };

  // ---- entry: coalesced ids + scattered se/ve prefetch ----
  if (t < 64) sRank[t] = rankArr[pbase + t];
  int eid = pbase + arow;
  int snd = senders[eid];
  const unsigned short* seb = s_upb + (size_t)snd * 64;
  const unsigned short* veb = v_upb + (size_t)snd * 96;
  short8 se0 = *(const short8*)&seb[kgrp * 8];
  short8 se1 = *(const short8*)&seb[32 + kgrp * 8];
  short8 ve0 = *(const short8*)&veb[24 * kgrp];
  short8 ve1 = *(const short8*)&veb[24 * kgrp + 8];
  short8 ve2 = *(const short8*)&veb[24 * kgrp + 16];
  float vx = vectors[(size_t)eid * 3 + 0];
  float vy = vectors[(size_t)eid * 3 + 1];
  float vz = vectors[(size_t)eid * 3 + 2];
  float nrm = sqrtf(vx * vx + vy * vy + vz * vz) + 1e-12f;
  float ysc = Y1C / nrm;
  float y0 = vx * ysc, y1 = vy * ysc, y2 = vz * ysc;

  // ---- layer 1: h1 = silu(rbf @ W1), rbf coalesced ----
  S8 a1;
  a1.u[0] = a1.u[1] = a1.u[2] = a1.u[3] = 0u;
  if (kgrp == 0) {
    float4 ra = *(const float4*)(rbf + (size_t)eid * 8);
    float4 rb = *(const float4*)(rbf + (size_t)eid * 8 + 4);
    a1.u[0] = packbf(ra.x, ra.y);
    a1.u[1] = packbf(ra.z, ra.w);
    a1.u[2] = packbf(rb.x, rb.y);
    a1.u[3] = packbf(rb.z, rb.w);
  }
#pragma unroll
  for (int ct = 0; ct < 4; ct++) {
    short8 b = *(const short8*)&W1p[(ct * 16 + rl) * 32 + kgrp * 8];
    f32x4 acc = {0.f, 0.f, 0.f, 0.f};
    acc = __builtin_amdgcn_mfma_f32_16x16x32_bf16(a1.v, b, acc, 0, 0, 0);
#pragma unroll
    for (int rr = 0; rr < 4; rr++)
      sH[(crow + rr) * 72 + ct * 16 + rl] = f2bf(silu(acc[rr]));
  }

  // ---- layer 2 ----
  {
    short8 a20 = *(const short8*)&sH[arow * 72 + kgrp * 8];
    short8 a21 = *(const short8*)&sH[arow * 72 + 32 + kgrp * 8];
#pragma unroll
    for (int ct = 0; ct < 4; ct++) {
      const unsigned short* wb = &W2p[(ct * 16 + rl) * 64];
      short8 b0 = *(const short8*)&wb[kgrp * 8];
      short8 b1 = *(const short8*)&wb[32 + kgrp * 8];
      f32x4 acc = {0.f, 0.f, 0.f, 0.f};
      acc = __builtin_amdgcn_mfma_f32_16x16x32_bf16(a20, b0, acc, 0, 0, 0);
      acc = __builtin_amdgcn_mfma_f32_16x16x32_bf16(a21, b1, acc, 0, 0, 0);
#pragma unroll
      for (int rr = 0; rr < 4; rr++)
        sH[(crow + rr) * 72 + ct * 16 + rl] = f2bf(silu(acc[rr]));
    }
  }

  // ---- layer 3: mix -> sMix (wave-private rows) ----
  {
    short8 a30 = *(const short8*)&sH[arow * 72 + kgrp * 8];
    short8 a31 = *(const short8*)&sH[arow * 72 + 32 + kgrp * 8];
#pragma unroll
    for (int nt = 0; nt < 12; nt++) {
      int cc = nt * 16 + rl;
      const unsigned short* wb = &W3b[cc * 64];
      short8 b0 = *(const short8*)&wb[kgrp * 8];
      short8 b1 = *(const short8*)&wb[32 + kgrp * 8];
      f32x4 acc = {0.f, 0.f, 0.f, 0.f};
      acc = __builtin_amdgcn_mfma_f32_16x16x32_bf16(a30, b0, acc, 0, 0, 0);
      acc = __builtin_amdgcn_mfma_f32_16x16x32_bf16(a31, b1, acc, 0, 0, 0);
#pragma unroll
      for (int rr = 0; rr < 4; rr++)
        sMix[(crow + rr) * 200 + cc] = f2bf(acc[rr]);
    }
  }

  // ---- ph3: build down-proj A-fragments in registers ----
  // msg_s ch k: [0,64)=se[k]*mix[k]; [64,96)=dot(ve[c],y)*mix[64+c] (1/sqrt3 in W3b)
  // msg_v ch c, comp i: [0,32)=ve3[c][i]*mixv[c]; [32,96)=se[c-32]*y_i*mixv[c]
  const unsigned short* mrow = &sMix[arow * 200];
  S8 as0, as1, as2, mvp1, mvp2, mvp3;
  {
    short8 m = *(const short8*)&mrow[kgrp * 8];
#pragma unroll
    for (int q = 0; q < 4; q++)
      as0.u[q] = packbf(bfe(se0, 2 * q) * bfe(m, 2 * q),
                        bfe(se0, 2 * q + 1) * bfe(m, 2 * q + 1));
  }
  {
    short8 m = *(const short8*)&mrow[32 + kgrp * 8];
#pragma unroll
    for (int q = 0; q < 4; q++)
      as1.u[q] = packbf(bfe(se1, 2 * q) * bfe(m, 2 * q),
                        bfe(se1, 2 * q + 1) * bfe(m, 2 * q + 1));
  }
  {
    short8 m = *(const short8*)&mrow[64 + kgrp * 8];
#pragma unroll
    for (int q = 0; q < 4; q++) {
      float e0, e1, e2, f0, f1, f2;
      // flat ve element j = comp (j%3) of channel kgrp*8 + j/3
      if (6 * q < 8) e0 = bfe(ve0, 6 * q); else if (6 * q < 16) e0 = bfe(ve1, 6 * q - 8); else e0 = bfe(ve2, 6 * q - 16);
      if (6 * q + 1 < 8) e1 = bfe(ve0, 6 * q + 1); else if (6 * q + 1 < 16) e1 = bfe(ve1, 6 * q - 7); else e1 = bfe(ve2, 6 * q - 15);
      if (6 * q + 2 < 8) e2 = bfe(ve0, 6 * q + 2); else if (6 * q + 2 < 16) e2 = bfe(ve1, 6 * q - 6); else e2 = bfe(ve2, 6 * q - 14);
      if (6 * q + 3 < 8) f0 = bfe(ve0, 6 * q + 3); else if (6 * q + 3 < 16) f0 = bfe(ve1, 6 * q - 5); else f0 = bfe(ve2, 6 * q - 13);
      if (6 * q + 4 < 8) f1 = bfe(ve0, 6 * q + 4); else if (6 * q + 4 < 16) f1 = bfe(ve1, 6 * q - 4); else f1 = bfe(ve2, 6 * q - 12);
      if (6 * q + 5 < 8) f2 = bfe(ve0, 6 * q + 5); else if (6 * q + 5 < 16) f2 = bfe(ve1, 6 * q - 3); else f2 = bfe(ve2, 6 * q - 11);
      float da = e0 * y0 + e1 * y1 + e2 * y2;
      float db = f0 * y0 + f1 * y1 + f2 * y2;
      as2.u[q] = packbf(da * bfe(m, 2 * q), db * bfe(m, 2 * q + 1));
    }
  }
  mvp1.v = *(const short8*)&mrow[96 + kgrp * 8];
  mvp2.v = *(const short8*)&mrow[128 + kgrp * 8];
  mvp3.v = *(const short8*)&mrow[160 + kgrp * 8];
  __syncthreads();  // BARRIER 1: sMix reads done before fp8 staging aliases it

  // ---- ph4: down-proj MFMA -> fp8 -> LDS stage (stride 232) ----
  unsigned char* edL = (unsigned char*)sMix;
#pragma unroll
  for (int ot = 0; ot < 8; ot++) {
    int col = ot * 16 + rl;
    const unsigned short* wb = &Wdsb[col * 96];
    short8 b0 = *(const short8*)&wb[kgrp * 8];
    short8 b1 = *(const short8*)&wb[32 + kgrp * 8];
    short8 b2 = *(const short8*)&wb[64 + kgrp * 8];
    f32x4 acc = {0.f, 0.f, 0.f, 0.f};
    acc = __builtin_amdgcn_mfma_f32_16x16x32_bf16(as0.v, b0, acc, 0, 0, 0);
    acc = __builtin_amdgcn_mfma_f32_16x16x32_bf16(as1.v, b1, acc, 0, 0, 0);
    acc = __builtin_amdgcn_mfma_f32_16x16x32_bf16(as2.v, b2, acc, 0, 0, 0);
#pragma unroll
    for (int rr = 0; rr < 4; rr++)
      edL[(crow + rr) * 232 + col] = f2fp8(acc[rr]);
  }
  float yarr[3] = {y0, y1, y2};
#pragma unroll
  for (int i = 0; i < 3; i++) {
    S8 av0, av1, av2;
#pragma unroll
    for (int q = 0; q < 4; q++) {
      float g0, g1;
      int ja = 6 * q + i, jb = 6 * q + 3 + i;  // compile-time in unrolled loop
      if (ja < 8) g0 = bfe(ve0, ja); else if (ja < 16) g0 = bfe(ve1, ja - 8); else g0 = bfe(ve2, ja - 16);
      if (jb < 8) g1 = bfe(ve0, jb); else if (jb < 16) g1 = bfe(ve1, jb - 8); else g1 = bfe(ve2, jb - 16);
      av0.u[q] = packbf(g0 * bfe(mvp1.v, 2 * q), g1 * bfe(mvp1.v, 2 * q + 1));
      av1.u[q] = packbf(bfe(se0, 2 * q) * yarr[i] * bfe(mvp2.v, 2 * q),
                        bfe(se0, 2 * q + 1) * yarr[i] * bfe(mvp2.v, 2 * q + 1));
      av2.u[q] = packbf(bfe(se1, 2 * q) * yarr[i] * bfe(mvp3.v, 2 * q),
                        bfe(se1, 2 * q + 1) * yarr[i] * bfe(mvp3.v, 2 * q + 1));
    }
#pragma unroll
    for (int ot = 0; ot < 2; ot++) {
      int o = ot * 16 + rl;
      const unsigned short* wb = &Wdvb[o * 96];
      short8 b0 = *(const short8*)&wb[kgrp * 8];
      short8 b1 = *(const short8*)&wb[32 + kgrp * 8];
      short8 b2 = *(const short8*)&wb[64 + kgrp * 8];
      f32x4 acc = {0.f, 0.f, 0.f, 0.f};
      acc = __builtin_amdgcn_mfma_f32_16x16x32_bf16(av0.v, b0, acc, 0, 0, 0);
      acc = __builtin_amdgcn_mfma_f32_16x16x32_bf16(av1.v, b1, acc, 0, 0, 0);
      acc = __builtin_amdgcn_mfma_f32_16x16x32_bf16(av2.v, b2, acc, 0, 0, 0);
#pragma unroll
      for (int rr = 0; rr < 4; rr++)
        edL[(crow + rr) * 232 + 128 + o * 3 + i] = f2fp8(acc[rr]);
    }
  }
  __syncthreads();  // BARRIER 2: staging + sRank complete

  // scatter copy-out: row r -> edown[rank[pbase+r]*224]
  {
    int row = t >> 2, q = t & 3;
    const unsigned* src = (const unsigned*)(edL + row * 232 + q * 56);
    unsigned* dst = (unsigned*)(edown + (size_t)sRank[row] * 224 + q * 56);
#pragma unroll
    for (int j = 0; j < 14; j++) dst[j] = src[j];
  }
}

// ---------------- gather: uint4 streaming segmented sum + skip + gate ----------------
__global__ __launch_bounds__(256) void gather_out4(
    const float* __restrict__ nf, const int* __restrict__ species,
    const int* __restrict__ prefix, const unsigned char* __restrict__ edown,
    const unsigned short* __restrict__ Wssb,
    const unsigned short* __restrict__ Wsvb, float* __restrict__ out) {
  int n = blockIdx.x;
  int t = threadIdx.x;
  __shared__ float sNF[160];
  __shared__ float sPart[16 * 224];
  __shared__ float sEd[224];
  __shared__ float sF[224];
  if (t < 160) sNF[t] = nf[(size_t)n * 160 + t];
  int beg = prefix[n], end = prefix[n + 1];
  if (t < 224) {
    int u = t % 14, rg = t / 14;  // u: which uint4 of the row; rg: row group
    float a[16];
#pragma unroll
    for (int j = 0; j < 16; j++) a[j] = 0.f;
    for (int s = beg + rg; s < end; s += 16) {
      uint4 v = *(const uint4*)(edown + (size_t)s * 224 + u * 16);
      unsigned w[4] = {v.x, v.y, v.z, v.w};
#pragma unroll
      for (int p = 0; p < 4; p++) {
        a[4 * p + 0] += fp82f(w[p] & 0xFF);
        a[4 * p + 1] += fp82f((w[p] >> 8) & 0xFF);
        a[4 * p + 2] += fp82f((w[p] >> 16) & 0xFF);
        a[4 * p + 3] += fp82f(w[p] >> 24);
      }
    }
#pragma unroll
    for (int j = 0; j < 16; j += 4)
      *(float4*)&sPart[rg * 224 + u * 16 + j] = *(float4*)&a[j];
  }
  __syncthreads();
  if (t < 224) {
    float s = 0.f;
#pragma unroll
    for (int rg = 0; rg < 16; rg++) s += sPart[rg * 224 + t];
    sEd[t] = s;
  }
  __syncthreads();
  int spec = species[n];
  if (t < 128) {
    const unsigned short* wsk = Wssb + (size_t)spec * 8192;
    float b = 0.f;
#pragma unroll
    for (int k = 0; k < 64; k++) b += sNF[k] * bf2f(wsk[k * 128 + t]);
    sF[t] = sEd[t] + b;
  } else if (t < 224) {
    int j = t - 128;
    int c = j / 3, i = j - 3 * c;
    const unsigned short* wsk = Wsvb + (size_t)spec * 1024;
    float b = 0.f;
#pragma unroll
    for (int k = 0; k < 32; k++) b += sNF[64 + k * 3 + i] * bf2f(wsk[k * 32 + c]);
    sF[t] = sEd[t] + b;
  }
  __syncthreads();
  if (t < 96) {
    out[(size_t)n * 192 + t] = silu(sF[t]);
  } else if (t < 192) {
    int j = t - 96;
    int c = j / 3;
    out[(size_t)n * 192 + t] = sF[128 + j] * silu(sF[96 + c]);
  }
}

extern "C" void kernel_launch(void* const* d_in, const int* in_sizes, int n_in,
                              void* d_out, int out_size, void* d_ws, size_t ws_size,
                              hipStream_t stream) {
  const float* nf = (const float*)d_in[0];
  const float* vectors = (const float*)d_in[1];
  const float* rbf = (const float*)d_in[2];
  const int* species = (const int*)d_in[3];
  const int* senders = (const int*)d_in[4];
  const int* receivers = (const int*)d_in[5];
  const float* Wus = (const float*)d_in[6];
  const float* Wuv = (const float*)d_in[7];
  const float* W1 = (const float*)d_in[8];
  const float* W2 = (const float*)d_in[9];
  const float* W3 = (const float*)d_in[10];
  const float* Wds = (const float*)d_in[11];
  const float* Wdv = (const float*)d_in[12];
  const float* Wss = (const float*)d_in[13];
  const float* Wsv = (const float*)d_in[14];

  float* ws = (float*)d_ws;
  const unsigned short* W1p = (const unsigned short*)(ws + W_W1P);
  const unsigned short* W2p = (const unsigned short*)(ws + W_W2P);
  const unsigned short* W3b = (const unsigned short*)(ws + W_W3B);
  const unsigned short* Wdsb = (const unsigned short*)(ws + W_WDS);
  const unsigned short* Wdvb = (const unsigned short*)(ws + W_WDV);
  const unsigned short* Wssb = (const unsigned short*)(ws + W_WSS);
  const unsigned short* Wsvb = (const unsigned short*)(ws + W_WSV);
  unsigned short* s_upb = (unsigned short*)(ws + W_SUPB);
  unsigned short* v_upb = (unsigned short*)(ws + W_VUPB);
  int* deg = (int*)(ws + W_DEG);
  int* prefix = (int*)(ws + W_PRE);
  int* cursor = (int*)(ws + W_CUR);
  int* rankArr = (int*)(ws + W_RNK);
  unsigned char* edown = (unsigned char*)(ws + W_EDN);
  float* out = (float*)d_out;

  transpose_weights<<<16, 256, 0, stream>>>(W1, W2, W3, Wds, Wdv, Wss, Wsv, ws);
  up_kernel<<<NN, 256, 0, stream>>>(nf, Wus, Wuv, s_upb, v_upb);

  hipMemsetAsync(deg, 0, (size_t)NN * sizeof(int), stream);
  count_deg<<<(EE + 255) / 256, 256, 0, stream>>>(receivers, deg);
  scan_kernel<<<1, 1024, 0, stream>>>(deg, prefix, cursor);
  rank_kernel<<<(EE + 255) / 256, 256, 0, stream>>>(receivers, cursor, rankArr);
  edge_down4<<<EE / 64, 256, 0, stream>>>(rbf, vectors, senders, rankArr, W1p,
                                          W2p, W3b, Wdsb, Wdvb, s_upb, v_upb,
                                          edown);
  gather_out4<<<NN, 256, 0, stream>>>(nf, species, prefix, edown, Wssb, Wsvb,
                                      out);
}

// Round 10
// 336.527 us; speedup vs baseline: 24.7234x; 1.0379x over previous
//
#include <hip/hip_runtime.h>
#include <hip/hip_bf16.h>
#include <hip/hip_fp16.h>
#include <hip/hip_fp8.h>

#define NN 25000
#define EE 400000

#define SC_UP_S 0.125f
#define SC_UP_V 0.17677669529663689f
#define Y1C 0.48860251190291992f
#define SC_MLP1 0.35355339059327373f
#define SC_MLP2 0.125f
#define SC3 0.0013020833333333333f      // (1/8)*(1/96) folded into W3
#define INV_SQRT3 0.57735026918962584f  // folded into W3 cols 64..96
#define SC_DOWN 0.025515518153991442f   // (1/4)*(1/sqrt(96)) folded into Wd
#define SC_SKIP_S 0.125f                // folded into Wssb
#define SC_SKIP_V 0.17677669529663689f  // folded into Wsvb

typedef __attribute__((ext_vector_type(8))) short short8;
typedef __attribute__((ext_vector_type(4))) float f32x4;

#if defined(__has_builtin)
#if __has_builtin(__builtin_amdgcn_cvt_pk_fp8_f32)
#define HAS_HW_FP8_ENC 1
#endif
#if __has_builtin(__builtin_amdgcn_cvt_pk_f32_fp8)
#define HAS_HW_FP8_DEC 1
#endif
#endif
#ifndef HAS_HW_FP8_ENC
#define HAS_HW_FP8_ENC 0
#endif
#ifndef HAS_HW_FP8_DEC
#define HAS_HW_FP8_DEC 0
#endif

__device__ __forceinline__ float silu(float x) {
  return __fdividef(x, 1.f + __expf(-x));
}
__device__ __forceinline__ unsigned short f2bf(float f) {
  __hip_bfloat16 h = __float2bfloat16(f);  // HW cvt, RTNE
  return *reinterpret_cast<unsigned short*>(&h);
}
__device__ __forceinline__ float bf2f(unsigned short s) {
  return __uint_as_float(((unsigned)s) << 16);
}
__device__ __forceinline__ float bfe(short8 v, int idx) {  // idx compile-time
  return __uint_as_float(((unsigned)(unsigned short)v[idx]) << 16);
}
__device__ __forceinline__ unsigned packbf(float lo, float hi) {
  return ((unsigned)f2bf(hi) << 16) | (unsigned)f2bf(lo);
}
__device__ __forceinline__ unsigned char f2fp8_sw(float x) {
  __hip_fp8_e4m3 v(x);
  return (unsigned char)v.__x;
}
// pack two floats -> two fp8 bytes (low 16 bits of result)
__device__ __forceinline__ unsigned f2fp8x2(float a, float b) {
#if HAS_HW_FP8_ENC
  return (unsigned)__builtin_amdgcn_cvt_pk_fp8_f32(a, b, 0, false);
#else
  return (unsigned)f2fp8_sw(a) | ((unsigned)f2fp8_sw(b) << 8);
#endif
}
__device__ __forceinline__ float fp82f_sw(unsigned b) {
  __hip_fp8_e4m3 t;
  t.__x = (__hip_fp8_storage_t)b;
  return (float)t;
}
// decode 4 fp8 bytes of a dword
__device__ __forceinline__ void fp8x4dec(unsigned w, float* o) {
#if HAS_HW_FP8_DEC
  auto lo = __builtin_amdgcn_cvt_pk_f32_fp8((int)w, false);
  auto hi = __builtin_amdgcn_cvt_pk_f32_fp8((int)w, true);
  o[0] = lo[0]; o[1] = lo[1]; o[2] = hi[0]; o[3] = hi[1];
#else
  o[0] = fp82f_sw(w & 0xFF);
  o[1] = fp82f_sw((w >> 8) & 0xFF);
  o[2] = fp82f_sw((w >> 16) & 0xFF);
  o[3] = fp82f_sw(w >> 24);
#endif
}

// ---------------- workspace layout (4-byte word offsets) ----------------
#define W_W1P 0                         // 64x32 bf16 (K zero-padded 8->32)
#define W_W2P 1024                      // 64x64 bf16 [col][k]
#define W_W3B 3072                      // 192x64 bf16 [col][k]
#define W_WDS 9216                      // 128x96 bf16 [col][k]
#define W_WDV 15360                     // 32x96 bf16 [col][k]
#define W_WSS 16896                     // 4x64x128 bf16 (skip_s, scale folded)
#define W_WSV 33280                     // 4x32x32 bf16 (skip_v, scale folded)
#define W_SUPB 35328                    // NN*64 bf16
#define W_VUPB (W_SUPB + NN * 32)       // NN*96 bf16
#define W_DEG (W_VUPB + NN * 48)
#define W_PRE (W_DEG + NN)
#define W_CUR (W_PRE + NN + 8)
#define W_RNK (W_CUR + NN)              // rank[e] = sorted position
#define W_EDN (W_RNK + EE)              // fp8: EE*224 bytes = EE*56 words
#define W_END (W_EDN + EE * 56)         // ~99.6 MB

// ---------------- setup: weight transforms ----------------
__global__ __launch_bounds__(256) void transpose_weights(
    const float* __restrict__ W1, const float* __restrict__ W2,
    const float* __restrict__ W3, const float* __restrict__ Wds,
    const float* __restrict__ Wdv, const float* __restrict__ Wss,
    const float* __restrict__ Wsv, float* __restrict__ ws) {
  int t = blockIdx.x * 256 + threadIdx.x;
  int stride = gridDim.x * 256;
  unsigned short* W1p = (unsigned short*)(ws + W_W1P);
  unsigned short* W2p = (unsigned short*)(ws + W_W2P);
  unsigned short* W3b = (unsigned short*)(ws + W_W3B);
  unsigned short* Wdsb = (unsigned short*)(ws + W_WDS);
  unsigned short* Wdvb = (unsigned short*)(ws + W_WDV);
  unsigned short* Wssb = (unsigned short*)(ws + W_WSS);
  unsigned short* Wsvb = (unsigned short*)(ws + W_WSV);
  for (int i = t; i < 2048; i += stride) {  // W1p[c*32+k], k<8 real
    int c = i >> 5, k = i & 31;
    W1p[i] = (k < 8) ? f2bf(W1[k * 64 + c] * SC_MLP1) : (unsigned short)0;
  }
  for (int i = t; i < 4096; i += stride) {  // W2p[c*64+k]
    int c = i >> 6, k = i & 63;
    W2p[i] = f2bf(W2[k * 64 + c] * SC_MLP2);
  }
  for (int i = t; i < 12288; i += stride) { // W3b[c*64+k]; 1/sqrt3 fold c in [64,96)
    int c = i >> 6, k = i & 63;
    float sc = (c >= 64 && c < 96) ? (SC3 * INV_SQRT3) : SC3;
    W3b[i] = f2bf(W3[k * 192 + c] * sc);
  }
  for (int i = t; i < 12288; i += stride) { // Wdsb[o*96+k]
    int o = i / 96, k = i - 96 * o;
    Wdsb[i] = f2bf(Wds[k * 128 + o] * SC_DOWN);
  }
  for (int i = t; i < 3072; i += stride) {  // Wdvb[o*96+k]
    int o = i / 96, k = i - 96 * o;
    Wdvb[i] = f2bf(Wdv[k * 32 + o] * SC_DOWN);
  }
  for (int i = t; i < 32768; i += stride)   // Wssb: same layout, scale folded
    Wssb[i] = f2bf(Wss[i] * SC_SKIP_S);
  for (int i = t; i < 4096; i += stride)    // Wsvb
    Wsvb[i] = f2bf(Wsv[i] * SC_SKIP_V);
}

// ---------------- per-node up-projection (fp32 math, bf16 out) ----------------
__global__ __launch_bounds__(256) void up_kernel(
    const float* __restrict__ nf, const float* __restrict__ Wus,
    const float* __restrict__ Wuv, unsigned short* __restrict__ s_upb,
    unsigned short* __restrict__ v_upb) {
  int n = blockIdx.x;
  int t = threadIdx.x;
  __shared__ float sv[160];
  if (t < 160) sv[t] = nf[n * 160 + t];
  __syncthreads();
  if (t < 64) {
    float a = 0.f;
#pragma unroll
    for (int k = 0; k < 64; k++) a += sv[k] * Wus[k * 64 + t];
    s_upb[n * 64 + t] = f2bf(a * SC_UP_S);
  } else if (t < 160) {
    int j = t - 64;
    int c = j / 3, i = j - 3 * c;
    float a = 0.f;
#pragma unroll
    for (int k = 0; k < 32; k++) a += sv[64 + k * 3 + i] * Wuv[k * 32 + c];
    v_upb[n * 96 + j] = f2bf(a * SC_UP_V);
  }
}

// ---------------- counting sort (rank only) ----------------
__global__ __launch_bounds__(256) void count_deg(
    const int* __restrict__ receivers, int* __restrict__ deg) {
  int e = blockIdx.x * 256 + threadIdx.x;
  if (e < EE) atomicAdd(&deg[receivers[e]], 1);
}

__global__ __launch_bounds__(1024) void scan_kernel(
    const int* __restrict__ deg, int* __restrict__ prefix,
    int* __restrict__ cursor) {
  __shared__ int waveSums[16];
  __shared__ int sCarry;
  int t = threadIdx.x;
  int lane = t & 63, wv = t >> 6;
  if (t == 0) sCarry = 0;
  __syncthreads();
  for (int base = 0; base < NN; base += 1024) {
    int i = base + t;
    int x = (i < NN) ? deg[i] : 0;
    int v = x;
#pragma unroll
    for (int d = 1; d < 64; d <<= 1) {
      int u = __shfl_up(v, d, 64);
      if (lane >= d) v += u;
    }
    if (lane == 63) waveSums[wv] = v;
    __syncthreads();
    if (wv == 0 && lane < 16) {
      int s = waveSums[lane];
#pragma unroll
      for (int d = 1; d < 16; d <<= 1) {
        int u = __shfl_up(s, d, 64);
        if (lane >= d) s += u;
      }
      waveSums[lane] = s;
    }
    __syncthreads();
    int waveOff = (wv == 0) ? 0 : waveSums[wv - 1];
    int incl = v + waveOff + sCarry;
    if (i < NN) {
      prefix[i] = incl - x;
      cursor[i] = incl - x;
    }
    __syncthreads();
    if (t == 1023) sCarry = incl;
    __syncthreads();
  }
  if (t == 0) prefix[NN] = sCarry;
}

__global__ __launch_bounds__(256) void rank_kernel(
    const int* __restrict__ receivers, int* __restrict__ cursor,
    int* __restrict__ rankArr) {
  int e = blockIdx.x * 256 + threadIdx.x;
  if (e < EE) {
    int r = receivers[e];
    rankArr[e] = atomicAdd(&cursor[r], 1);
  }
}

// ---------------- fused edge pipeline: natural order, scatter-write ----------------
__global__ __launch_bounds__(256, 4) void edge_down4(
    const float* __restrict__ rbf, const float* __restrict__ vectors,
    const int* __restrict__ senders, const int* __restrict__ rankArr,
    const unsigned short* __restrict__ W1p,
    const unsigned short* __restrict__ W2p,
    const unsigned short* __restrict__ W3b,
    const unsigned short* __restrict__ Wdsb,
    const unsigned short* __restrict__ Wdvb,
    const unsigned short* __restrict__ s_upb,
    const unsigned short* __restrict__ v_upb,
    unsigned char* __restrict__ edown) {
  __shared__ unsigned short sH[64 * 72];     // h1 then h2 (wave-private rows)
  __shared__ unsigned short sMix[64 * 200];  // mix; then fp8 staging (stride 232B)
  __shared__ int sRank[64];

  int t = threadIdx.x;
  int pbase = blockIdx.x * 64;
  int lane = t & 63;
  int wv = t >> 6;
  int rl = lane & 15;
  int kgrp = lane >> 4;
  int arow = 16 * wv + rl;        // this lane's edge row
  int crow = 16 * wv + kgrp * 4;  // C rows base (+rr)

  union S8 { short8 v; unsigned u[4]; };

  // ---- entry: coalesced ids + scattered se/ve prefetch ----
  if (t < 64) sRank[t] = rankArr[pbase + t];
  int eid = pbase + arow;
  int snd = senders[eid];
  const unsigned short* seb = s_upb + (size_t)snd * 64;
  const unsigned short* veb = v_upb + (size_t)snd * 96;
  short8 se0 = *(const short8*)&seb[kgrp * 8];
  short8 se1 = *(const short8*)&seb[32 + kgrp * 8];
  short8 ve0 = *(const short8*)&veb[24 * kgrp];
  short8 ve1 = *(const short8*)&veb[24 * kgrp + 8];
  short8 ve2 = *(const short8*)&veb[24 * kgrp + 16];
  float vx = vectors[(size_t)eid * 3 + 0];
  float vy = vectors[(size_t)eid * 3 + 1];
  float vz = vectors[(size_t)eid * 3 + 2];
  float nrm = sqrtf(vx * vx + vy * vy + vz * vz) + 1e-12f;
  float ysc = Y1C / nrm;
  float y0 = vx * ysc, y1 = vy * ysc, y2 = vz * ysc;

  // ---- layer 1: h1 = silu(rbf @ W1), rbf coalesced ----
  S8 a1;
  a1.u[0] = a1.u[1] = a1.u[2] = a1.u[3] = 0u;
  if (kgrp == 0) {
    float4 ra = *(const float4*)(rbf + (size_t)eid * 8);
    float4 rb = *(const float4*)(rbf + (size_t)eid * 8 + 4);
    a1.u[0] = packbf(ra.x, ra.y);
    a1.u[1] = packbf(ra.z, ra.w);
    a1.u[2] = packbf(rb.x, rb.y);
    a1.u[3] = packbf(rb.z, rb.w);
  }
#pragma unroll
  for (int ct = 0; ct < 4; ct++) {
    short8 b = *(const short8*)&W1p[(ct * 16 + rl) * 32 + kgrp * 8];
    f32x4 acc = {0.f, 0.f, 0.f, 0.f};
    acc = __builtin_amdgcn_mfma_f32_16x16x32_bf16(a1.v, b, acc, 0, 0, 0);
#pragma unroll
    for (int rr = 0; rr < 4; rr++)
      sH[(crow + rr) * 72 + ct * 16 + rl] = f2bf(silu(acc[rr]));
  }

  // ---- layer 2 ----
  {
    short8 a20 = *(const short8*)&sH[arow * 72 + kgrp * 8];
    short8 a21 = *(const short8*)&sH[arow * 72 + 32 + kgrp * 8];
    short8 b0s[4], b1s[4];
#pragma unroll
    for (int ct = 0; ct < 4; ct++) {
      const unsigned short* wb = &W2p[(ct * 16 + rl) * 64];
      b0s[ct] = *(const short8*)&wb[kgrp * 8];
      b1s[ct] = *(const short8*)&wb[32 + kgrp * 8];
    }
#pragma unroll
    for (int ct = 0; ct < 4; ct++) {
      f32x4 acc = {0.f, 0.f, 0.f, 0.f};
      acc = __builtin_amdgcn_mfma_f32_16x16x32_bf16(a20, b0s[ct], acc, 0, 0, 0);
      acc = __builtin_amdgcn_mfma_f32_16x16x32_bf16(a21, b1s[ct], acc, 0, 0, 0);
#pragma unroll
      for (int rr = 0; rr < 4; rr++)
        sH[(crow + rr) * 72 + ct * 16 + rl] = f2bf(silu(acc[rr]));
    }
  }

  // ---- layer 3: mix -> sMix (wave-private rows), chunked B preload ----
  {
    short8 a30 = *(const short8*)&sH[arow * 72 + kgrp * 8];
    short8 a31 = *(const short8*)&sH[arow * 72 + 32 + kgrp * 8];
#pragma unroll
    for (int half = 0; half < 2; half++) {
      short8 b0s[6], b1s[6];
#pragma unroll
      for (int j = 0; j < 6; j++) {
        int cc = (half * 6 + j) * 16 + rl;
        const unsigned short* wb = &W3b[cc * 64];
        b0s[j] = *(const short8*)&wb[kgrp * 8];
        b1s[j] = *(const short8*)&wb[32 + kgrp * 8];
      }
#pragma unroll
      for (int j = 0; j < 6; j++) {
        int cc = (half * 6 + j) * 16 + rl;
        f32x4 acc = {0.f, 0.f, 0.f, 0.f};
        acc = __builtin_amdgcn_mfma_f32_16x16x32_bf16(a30, b0s[j], acc, 0, 0, 0);
        acc = __builtin_amdgcn_mfma_f32_16x16x32_bf16(a31, b1s[j], acc, 0, 0, 0);
#pragma unroll
        for (int rr = 0; rr < 4; rr++)
          sMix[(crow + rr) * 200 + cc] = f2bf(acc[rr]);
      }
    }
  }

  // ---- ph3: build down-proj A-fragments in registers ----
  const unsigned short* mrow = &sMix[arow * 200];
  S8 as0, as1, as2, mvp1, mvp2, mvp3;
  {
    short8 m = *(const short8*)&mrow[kgrp * 8];
#pragma unroll
    for (int q = 0; q < 4; q++)
      as0.u[q] = packbf(bfe(se0, 2 * q) * bfe(m, 2 * q),
                        bfe(se0, 2 * q + 1) * bfe(m, 2 * q + 1));
  }
  {
    short8 m = *(const short8*)&mrow[32 + kgrp * 8];
#pragma unroll
    for (int q = 0; q < 4; q++)
      as1.u[q] = packbf(bfe(se1, 2 * q) * bfe(m, 2 * q),
                        bfe(se1, 2 * q + 1) * bfe(m, 2 * q + 1));
  }
  {
    short8 m = *(const short8*)&mrow[64 + kgrp * 8];
#pragma unroll
    for (int q = 0; q < 4; q++) {
      float e0, e1, e2, f0, f1, f2;
      // flat ve element j = comp (j%3) of channel kgrp*8 + j/3
      if (6 * q < 8) e0 = bfe(ve0, 6 * q); else if (6 * q < 16) e0 = bfe(ve1, 6 * q - 8); else e0 = bfe(ve2, 6 * q - 16);
      if (6 * q + 1 < 8) e1 = bfe(ve0, 6 * q + 1); else if (6 * q + 1 < 16) e1 = bfe(ve1, 6 * q - 7); else e1 = bfe(ve2, 6 * q - 15);
      if (6 * q + 2 < 8) e2 = bfe(ve0, 6 * q + 2); else if (6 * q + 2 < 16) e2 = bfe(ve1, 6 * q - 6); else e2 = bfe(ve2, 6 * q - 14);
      if (6 * q + 3 < 8) f0 = bfe(ve0, 6 * q + 3); else if (6 * q + 3 < 16) f0 = bfe(ve1, 6 * q - 5); else f0 = bfe(ve2, 6 * q - 13);
      if (6 * q + 4 < 8) f1 = bfe(ve0, 6 * q + 4); else if (6 * q + 4 < 16) f1 = bfe(ve1, 6 * q - 4); else f1 = bfe(ve2, 6 * q - 12);
      if (6 * q + 5 < 8) f2 = bfe(ve0, 6 * q + 5); else if (6 * q + 5 < 16) f2 = bfe(ve1, 6 * q - 3); else f2 = bfe(ve2, 6 * q - 11);
      float da = e0 * y0 + e1 * y1 + e2 * y2;
      float db = f0 * y0 + f1 * y1 + f2 * y2;
      as2.u[q] = packbf(da * bfe(m, 2 * q), db * bfe(m, 2 * q + 1));
    }
  }
  mvp1.v = *(const short8*)&mrow[96 + kgrp * 8];
  mvp2.v = *(const short8*)&mrow[128 + kgrp * 8];
  mvp3.v = *(const short8*)&mrow[160 + kgrp * 8];
  __syncthreads();  // BARRIER 1: sMix reads done before fp8 staging aliases it

  // ---- ph4: down-proj MFMA -> fp8 (HW pk cvt) -> LDS stage (stride 232) ----
  unsigned char* edL = (unsigned char*)sMix;
#pragma unroll
  for (int half = 0; half < 2; half++) {
    short8 b0s[4], b1s[4], b2s[4];
#pragma unroll
    for (int j = 0; j < 4; j++) {
      int col = (half * 4 + j) * 16 + rl;
      const unsigned short* wb = &Wdsb[col * 96];
      b0s[j] = *(const short8*)&wb[kgrp * 8];
      b1s[j] = *(const short8*)&wb[32 + kgrp * 8];
      b2s[j] = *(const short8*)&wb[64 + kgrp * 8];
    }
#pragma unroll
    for (int j = 0; j < 4; j++) {
      int col = (half * 4 + j) * 16 + rl;
      f32x4 acc = {0.f, 0.f, 0.f, 0.f};
      acc = __builtin_amdgcn_mfma_f32_16x16x32_bf16(as0.v, b0s[j], acc, 0, 0, 0);
      acc = __builtin_amdgcn_mfma_f32_16x16x32_bf16(as1.v, b1s[j], acc, 0, 0, 0);
      acc = __builtin_amdgcn_mfma_f32_16x16x32_bf16(as2.v, b2s[j], acc, 0, 0, 0);
      unsigned p01 = f2fp8x2(acc[0], acc[1]);
      unsigned p23 = f2fp8x2(acc[2], acc[3]);
      edL[(crow + 0) * 232 + col] = (unsigned char)p01;
      edL[(crow + 1) * 232 + col] = (unsigned char)(p01 >> 8);
      edL[(crow + 2) * 232 + col] = (unsigned char)p23;
      edL[(crow + 3) * 232 + col] = (unsigned char)(p23 >> 8);
    }
  }
  float yarr[3] = {y0, y1, y2};
#pragma unroll
  for (int i = 0; i < 3; i++) {
    S8 av0, av1, av2;
#pragma unroll
    for (int q = 0; q < 4; q++) {
      float g0, g1;
      int ja = 6 * q + i, jb = 6 * q + 3 + i;  // compile-time in unrolled loop
      if (ja < 8) g0 = bfe(ve0, ja); else if (ja < 16) g0 = bfe(ve1, ja - 8); else g0 = bfe(ve2, ja - 16);
      if (jb < 8) g1 = bfe(ve0, jb); else if (jb < 16) g1 = bfe(ve1, jb - 8); else g1 = bfe(ve2, jb - 16);
      av0.u[q] = packbf(g0 * bfe(mvp1.v, 2 * q), g1 * bfe(mvp1.v, 2 * q + 1));
      av1.u[q] = packbf(bfe(se0, 2 * q) * yarr[i] * bfe(mvp2.v, 2 * q),
                        bfe(se0, 2 * q + 1) * yarr[i] * bfe(mvp2.v, 2 * q + 1));
      av2.u[q] = packbf(bfe(se1, 2 * q) * yarr[i] * bfe(mvp3.v, 2 * q),
                        bfe(se1, 2 * q + 1) * yarr[i] * bfe(mvp3.v, 2 * q + 1));
    }
#pragma unroll
    for (int ot = 0; ot < 2; ot++) {
      int o = ot * 16 + rl;
      const unsigned short* wb = &Wdvb[o * 96];
      short8 b0 = *(const short8*)&wb[kgrp * 8];
      short8 b1 = *(const short8*)&wb[32 + kgrp * 8];
      short8 b2 = *(const short8*)&wb[64 + kgrp * 8];
      f32x4 acc = {0.f, 0.f, 0.f, 0.f};
      acc = __builtin_amdgcn_mfma_f32_16x16x32_bf16(av0.v, b0, acc, 0, 0, 0);
      acc = __builtin_amdgcn_mfma_f32_16x16x32_bf16(av1.v, b1, acc, 0, 0, 0);
      acc = __builtin_amdgcn_mfma_f32_16x16x32_bf16(av2.v, b2, acc, 0, 0, 0);
      unsigned p01 = f2fp8x2(acc[0], acc[1]);
      unsigned p23 = f2fp8x2(acc[2], acc[3]);
      edL[(crow + 0) * 232 + 128 + o * 3 + i] = (unsigned char)p01;
      edL[(crow + 1) * 232 + 128 + o * 3 + i] = (unsigned char)(p01 >> 8);
      edL[(crow + 2) * 232 + 128 + o * 3 + i] = (unsigned char)p23;
      edL[(crow + 3) * 232 + 128 + o * 3 + i] = (unsigned char)(p23 >> 8);
    }
  }
  __syncthreads();  // BARRIER 2: staging + sRank complete

  // scatter copy-out: row r -> edown[rank[pbase+r]*224]
  {
    int row = t >> 2, q = t & 3;
    const unsigned* src = (const unsigned*)(edL + row * 232 + q * 56);
    unsigned* dst = (unsigned*)(edown + (size_t)sRank[row] * 224 + q * 56);
#pragma unroll
    for (int j = 0; j < 14; j++) dst[j] = src[j];
  }
}

// ---------------- gather: uint4 streaming segmented sum + skip + gate ----------------
__global__ __launch_bounds__(256) void gather_out4(
    const float* __restrict__ nf, const int* __restrict__ species,
    const int* __restrict__ prefix, const unsigned char* __restrict__ edown,
    const unsigned short* __restrict__ Wssb,
    const unsigned short* __restrict__ Wsvb, float* __restrict__ out) {
  int n = blockIdx.x;
  int t = threadIdx.x;
  __shared__ float sNF[160];
  __shared__ float sPart[16 * 224];
  __shared__ float sEd[224];
  __shared__ float sF[224];
  if (t < 160) sNF[t] = nf[(size_t)n * 160 + t];
  int beg = prefix[n], end = prefix[n + 1];
  if (t < 224) {
    int u = t % 14, rg = t / 14;  // u: which uint4 of the row; rg: row group
    float a[16];
#pragma unroll
    for (int j = 0; j < 16; j++) a[j] = 0.f;
    for (int s = beg + rg; s < end; s += 16) {
      uint4 v = *(const uint4*)(edown + (size_t)s * 224 + u * 16);
      float d[4];
      fp8x4dec(v.x, d);
      a[0] += d[0]; a[1] += d[1]; a[2] += d[2]; a[3] += d[3];
      fp8x4dec(v.y, d);
      a[4] += d[0]; a[5] += d[1]; a[6] += d[2]; a[7] += d[3];
      fp8x4dec(v.z, d);
      a[8] += d[0]; a[9] += d[1]; a[10] += d[2]; a[11] += d[3];
      fp8x4dec(v.w, d);
      a[12] += d[0]; a[13] += d[1]; a[14] += d[2]; a[15] += d[3];
    }
#pragma unroll
    for (int j = 0; j < 16; j += 4)
      *(float4*)&sPart[rg * 224 + u * 16 + j] = *(float4*)&a[j];
  }
  __syncthreads();
  if (t < 224) {
    float s = 0.f;
#pragma unroll
    for (int rg = 0; rg < 16; rg++) s += sPart[rg * 224 + t];
    sEd[t] = s;
  }
  __syncthreads();
  int spec = species[n];
  if (t < 128) {
    const unsigned short* wsk = Wssb + (size_t)spec * 8192;
    float b = 0.f;
#pragma unroll
    for (int k = 0; k < 64; k++) b += sNF[k] * bf2f(wsk[k * 128 + t]);
    sF[t] = sEd[t] + b;
  } else if (t < 224) {
    int j = t - 128;
    int c = j / 3, i = j - 3 * c;
    const unsigned short* wsk = Wsvb + (size_t)spec * 1024;
    float b = 0.f;
#pragma unroll
    for (int k = 0; k < 32; k++) b += sNF[64 + k * 3 + i] * bf2f(wsk[k * 32 + c]);
    sF[t] = sEd[t] + b;
  }
  __syncthreads();
  if (t < 96) {
    out[(size_t)n * 192 + t] = silu(sF[t]);
  } else if (t < 192) {
    int j = t - 96;
    int c = j / 3;
    out[(size_t)n * 192 + t] = sF[128 + j] * silu(sF[96 + c]);
  }
}

extern "C" void kernel_launch(void* const* d_in, const int* in_sizes, int n_in,
                              void* d_out, int out_size, void* d_ws, size_t ws_size,
                              hipStream_t stream) {
  const float* nf = (const float*)d_in[0];
  const float* vectors = (const float*)d_in[1];
  const float* rbf = (const float*)d_in[2];
  const int* species = (const int*)d_in[3];
  const int* senders = (const int*)d_in[4];
  const int* receivers = (const int*)d_in[5];
  const float* Wus = (const float*)d_in[6];
  const float* Wuv = (const float*)d_in[7];
  const float* W1 = (const float*)d_in[8];
  const float* W2 = (const float*)d_in[9];
  const float* W3 = (const float*)d_in[10];
  const float* Wds = (const float*)d_in[11];
  const float* Wdv = (const float*)d_in[12];
  const float* Wss = (const float*)d_in[13];
  const float* Wsv = (const float*)d_in[14];

  float* ws = (float*)d_ws;
  const unsigned short* W1p = (const unsigned short*)(ws + W_W1P);
  const unsigned short* W2p = (const unsigned short*)(ws + W_W2P);
  const unsigned short* W3b = (const unsigned short*)(ws + W_W3B);
  const unsigned short* Wdsb = (const unsigned short*)(ws + W_WDS);
  const unsigned short* Wdvb = (const unsigned short*)(ws + W_WDV);
  const unsigned short* Wssb = (const unsigned short*)(ws + W_WSS);
  const unsigned short* Wsvb = (const unsigned short*)(ws + W_WSV);
  unsigned short* s_upb = (unsigned short*)(ws + W_SUPB);
  unsigned short* v_upb = (unsigned short*)(ws + W_VUPB);
  int* deg = (int*)(ws + W_DEG);
  int* prefix = (int*)(ws + W_PRE);
  int* cursor = (int*)(ws + W_CUR);
  int* rankArr = (int*)(ws + W_RNK);
  unsigned char* edown = (unsigned char*)(ws + W_EDN);
  float* out = (float*)d_out;

  transpose_weights<<<16, 256, 0, stream>>>(W1, W2, W3, Wds, Wdv, Wss, Wsv, ws);
  up_kernel<<<NN, 256, 0, stream>>>(nf, Wus, Wuv, s_upb, v_upb);

  hipMemsetAsync(deg, 0, (size_t)NN * sizeof(int), stream);
  count_deg<<<(EE + 255) / 256, 256, 0, stream>>>(receivers, deg);
  scan_kernel<<<1, 1024, 0, stream>>>(deg, prefix, cursor);
  rank_kernel<<<(EE + 255) / 256, 256, 0, stream>>>(receivers, cursor, rankArr);
  edge_down4<<<EE / 64, 256, 0, stream>>>(rbf, vectors, senders, rankArr, W1p,
                                          W2p, W3b, Wdsb, Wdvb, s_upb, v_upb,
                                          edown);
  gather_out4<<<NN, 256, 0, stream>>>(nf, species, prefix, edown, Wssb, Wsvb,
                                      out);
}